// Round 5
// baseline (1988.102 us; speedup 1.0000x reference)
//
#include <hip/hip_runtime.h>

#define N_NODES  100000
#define M_PAD    100096   // multiple of 128
#define N_EDGES  1600000
#define N_GRAPHS 512
#define IN_DIM   128
#define HID_DIM  256
#define OUT_DIM  128

#define NB       782      // buckets of 128 nodes: 782*128 = 100096
#define BCAP     3072     // mean 2048, sigma~45 -> +22 sigma headroom

typedef __bf16 bf16x8 __attribute__((ext_vector_type(8)));
typedef __bf16 bf16x4 __attribute__((ext_vector_type(4)));
typedef __bf16 bf16x2 __attribute__((ext_vector_type(2)));
typedef float  f32x4  __attribute__((ext_vector_type(4)));

// ---------------- x -> bf16 convert ----------------
__global__ __launch_bounds__(256) void convert_x_kernel(const float4* __restrict__ x4,
                                                        bf16x4* __restrict__ xb4, int n4) {
    int i = blockIdx.x * blockDim.x + threadIdx.x;
    if (i < n4) {
        float4 v = x4[i];
        bf16x4 h;
        h.x = (__bf16)v.x; h.y = (__bf16)v.y; h.z = (__bf16)v.z; h.w = (__bf16)v.w;
        xb4[i] = h;
    }
}

// ---------------- bucket edges by dst>>7, pack (src | dstLocal<<17) ----------------
__global__ __launch_bounds__(256) void bucket_kernel(const int* __restrict__ ei,
                                                     int* __restrict__ cursor,
                                                     unsigned* __restrict__ pairBuf) {
    int e = blockIdx.x * blockDim.x + threadIdx.x;
    if (e < N_EDGES) {
        int s = ei[e];
        int d = ei[N_EDGES + e];
        int b = d >> 7;
        int pos = atomicAdd(&cursor[b], 1);
        if (pos < BCAP)
            pairBuf[(size_t)b * BCAP + pos] = (unsigned)s | ((unsigned)(d & 127) << 17);
    }
}

// ---------------- fused aggregate: per-bucket LDS scatter-add ----------------
// A[v] = bf16( x[v] + sum_{edges e: dst(e)=v} x_bf16[src(e)] )
__global__ __launch_bounds__(256) void agg_kernel(const float* __restrict__ x,
                                                  const __bf16* __restrict__ xb,
                                                  const int* __restrict__ cursor,
                                                  const unsigned* __restrict__ pairBuf,
                                                  __bf16* __restrict__ A) {
    __shared__ float acc[128 * 128];   // 64 KB
    const int b = blockIdx.x;
    const int node0 = b << 7;
    const int tid = threadIdx.x;
    const int wave = tid >> 6, lane = tid & 63;

    // init acc with x (the 1*x term); pad rows -> 0
    for (int f = tid; f < 128 * 128; f += 256) {
        int node = node0 + (f >> 7);
        acc[f] = (node < N_NODES) ? x[(size_t)node * IN_DIM + (f & 127)] : 0.f;
    }
    __syncthreads();

    const int cnt = min(cursor[b], BCAP);
    const unsigned* pb = pairBuf + (size_t)b * BCAP;
    const int c0 = lane * 2;

    // 4-unrolled edge loop: 4 gathers in flight per wave to hide LLC latency
    int eb = wave * 4;
    for (; eb + 4 <= cnt; eb += 16) {
        unsigned w0 = pb[eb + 0], w1 = pb[eb + 1], w2 = pb[eb + 2], w3 = pb[eb + 3];
        int s0 = w0 & 0x1FFFF, s1 = w1 & 0x1FFFF, s2 = w2 & 0x1FFFF, s3 = w3 & 0x1FFFF;
        int d0 = w0 >> 17, d1 = w1 >> 17, d2 = w2 >> 17, d3 = w3 >> 17;
        bf16x2 v0 = *(const bf16x2*)(xb + (size_t)s0 * IN_DIM + c0);
        bf16x2 v1 = *(const bf16x2*)(xb + (size_t)s1 * IN_DIM + c0);
        bf16x2 v2 = *(const bf16x2*)(xb + (size_t)s2 * IN_DIM + c0);
        bf16x2 v3 = *(const bf16x2*)(xb + (size_t)s3 * IN_DIM + c0);
        __hip_atomic_fetch_add(&acc[d0 * 128 + c0 + 0], (float)v0.x, __ATOMIC_RELAXED, __HIP_MEMORY_SCOPE_WORKGROUP);
        __hip_atomic_fetch_add(&acc[d0 * 128 + c0 + 1], (float)v0.y, __ATOMIC_RELAXED, __HIP_MEMORY_SCOPE_WORKGROUP);
        __hip_atomic_fetch_add(&acc[d1 * 128 + c0 + 0], (float)v1.x, __ATOMIC_RELAXED, __HIP_MEMORY_SCOPE_WORKGROUP);
        __hip_atomic_fetch_add(&acc[d1 * 128 + c0 + 1], (float)v1.y, __ATOMIC_RELAXED, __HIP_MEMORY_SCOPE_WORKGROUP);
        __hip_atomic_fetch_add(&acc[d2 * 128 + c0 + 0], (float)v2.x, __ATOMIC_RELAXED, __HIP_MEMORY_SCOPE_WORKGROUP);
        __hip_atomic_fetch_add(&acc[d2 * 128 + c0 + 1], (float)v2.y, __ATOMIC_RELAXED, __HIP_MEMORY_SCOPE_WORKGROUP);
        __hip_atomic_fetch_add(&acc[d3 * 128 + c0 + 0], (float)v3.x, __ATOMIC_RELAXED, __HIP_MEMORY_SCOPE_WORKGROUP);
        __hip_atomic_fetch_add(&acc[d3 * 128 + c0 + 1], (float)v3.y, __ATOMIC_RELAXED, __HIP_MEMORY_SCOPE_WORKGROUP);
    }
    // residual (cnt not multiple of 4 per wave-slot)
    for (int e = eb; e < min(eb + 4, cnt); ++e) {
        unsigned w = pb[e];
        int s = w & 0x1FFFF, d = w >> 17;
        bf16x2 v = *(const bf16x2*)(xb + (size_t)s * IN_DIM + c0);
        __hip_atomic_fetch_add(&acc[d * 128 + c0 + 0], (float)v.x, __ATOMIC_RELAXED, __HIP_MEMORY_SCOPE_WORKGROUP);
        __hip_atomic_fetch_add(&acc[d * 128 + c0 + 1], (float)v.y, __ATOMIC_RELAXED, __HIP_MEMORY_SCOPE_WORKGROUP);
    }
    __syncthreads();

    // write out bf16, coalesced
    __bf16* Arow = A + (size_t)node0 * IN_DIM;
    for (int f2 = tid; f2 < 128 * 128 / 2; f2 += 256) {
        bf16x2 h;
        h.x = (__bf16)acc[f2 * 2 + 0];
        h.y = (__bf16)acc[f2 * 2 + 1];
        *(bf16x2*)(Arow + f2 * 2) = h;
    }
}

// ---------------- weight convert + transpose: Wt[n][k] = bf16(W[k][n]) ----------------
__global__ __launch_bounds__(256) void convert_transpose_kernel(const float* __restrict__ W,
                                                                __bf16* __restrict__ Wt,
                                                                int K, int N) {
    int i = blockIdx.x * blockDim.x + threadIdx.x;
    if (i < K * N) {
        int k = i / N, n = i % N;
        Wt[(size_t)n * K + k] = (__bf16)W[i];
    }
}

// ---------------- weight-stationary bf16 MFMA GEMM ----------------
template <int K, int N, bool RELU, bool POOL>
__global__ __launch_bounds__(256) void gemm_ws(const __bf16* __restrict__ A,
                                               const __bf16* __restrict__ Bt,
                                               const float* __restrict__ bias,
                                               void* __restrict__ C,
                                               const int* __restrict__ batch) {
    constexpr int KS = K / 32;
    constexpr int P  = 8 * KS;
    __shared__ __bf16 Bs[P * 64 * 8];

    const int tid  = threadIdx.x;
    const int wave = tid >> 6;
    const int lane = tid & 63;
    const int quad = lane >> 4, l16 = lane & 15;
    const int colbase = blockIdx.y * 128;

    for (int p = wave; p < P; p += 4) {
        int t = p / KS, s = p % KS;
        bf16x8 w = *(const bf16x8*)(Bt + (size_t)(colbase + t * 16 + l16) * K + s * 32 + quad * 8);
        *(bf16x8*)(Bs + ((size_t)p * 64 + lane) * 8) = w;
    }
    __syncthreads();

    const int strip = blockIdx.x * 4 + wave;
    const int r0 = strip * 32;

    bf16x8 a[2][KS];
    #pragma unroll
    for (int i = 0; i < 2; ++i)
        #pragma unroll
        for (int s = 0; s < KS; ++s)
            a[i][s] = *(const bf16x8*)(A + (size_t)(r0 + i * 16 + l16) * K + s * 32 + quad * 8);

    f32x4 acc[2][8] = {};
    #pragma unroll
    for (int s = 0; s < KS; ++s)
        #pragma unroll
        for (int t = 0; t < 8; ++t) {
            bf16x8 bfrag = *(const bf16x8*)(Bs + ((size_t)(t * KS + s) * 64 + lane) * 8);
            acc[0][t] = __builtin_amdgcn_mfma_f32_16x16x32_bf16(a[0][s], bfrag, acc[0][t], 0, 0, 0);
            acc[1][t] = __builtin_amdgcn_mfma_f32_16x16x32_bf16(a[1][s], bfrag, acc[1][t], 0, 0, 0);
        }

    if (!POOL) {
        #pragma unroll
        for (int i = 0; i < 2; ++i)
            #pragma unroll
            for (int rr = 0; rr < 4; ++rr) {
                size_t m = (size_t)r0 + i * 16 + quad * 4 + rr;
                #pragma unroll
                for (int t = 0; t < 8; ++t) {
                    int c = colbase + t * 16 + l16;
                    float v = acc[i][t][rr] + bias[c];
                    if (RELU) v = fmaxf(v, 0.f);
                    ((__bf16*)C)[m * N + c] = (__bf16)v;
                }
            }
    } else {
        float* out = (float*)C;
        int gfirst = (r0 < N_NODES) ? batch[r0] : -2;
        int glast  = (r0 + 31 < N_NODES) ? batch[r0 + 31] : -1;
        if (gfirst == glast) {
            #pragma unroll
            for (int t = 0; t < 8; ++t) {
                float sum = 0.f;
                #pragma unroll
                for (int i = 0; i < 2; ++i)
                    #pragma unroll
                    for (int rr = 0; rr < 4; ++rr) sum += acc[i][t][rr];
                sum += __shfl_xor(sum, 16, 64);
                sum += __shfl_xor(sum, 32, 64);
                if (quad == 0) {
                    int c = colbase + t * 16 + l16;
                    atomicAdd(out + (size_t)gfirst * N + c, sum + 32.f * bias[c]);
                }
            }
        } else {
            #pragma unroll
            for (int i = 0; i < 2; ++i)
                #pragma unroll
                for (int rr = 0; rr < 4; ++rr) {
                    int m = r0 + i * 16 + quad * 4 + rr;
                    if (m < N_NODES) {
                        int g = batch[m];
                        #pragma unroll
                        for (int t = 0; t < 8; ++t) {
                            int c = colbase + t * 16 + l16;
                            atomicAdd(out + (size_t)g * N + c, acc[i][t][rr] + bias[c]);
                        }
                    }
                }
        }
    }
}

extern "C" void kernel_launch(void* const* d_in, const int* in_sizes, int n_in,
                              void* d_out, int out_size, void* d_ws, size_t ws_size,
                              hipStream_t stream) {
    const float* x  = (const float*)d_in[0];
    const int*   ei = (const int*)d_in[1];
    const int*   bi = (const int*)d_in[2];
    const float* W1 = (const float*)d_in[3];
    const float* b1 = (const float*)d_in[4];
    const float* W2 = (const float*)d_in[5];
    const float* b2 = (const float*)d_in[6];
    const float* Wo = (const float*)d_in[7];
    const float* bo = (const float*)d_in[8];
    float* out = (float*)d_out;

    __bf16* A   = (__bf16*)d_ws;                       // [M_PAD][128]
    __bf16* H1  = A   + (size_t)M_PAD * IN_DIM;        // [M_PAD][256]
    __bf16* H2  = H1  + (size_t)M_PAD * HID_DIM;       // [M_PAD][256]
    __bf16* xb  = H2  + (size_t)M_PAD * HID_DIM;       // [N_NODES][128]
    __bf16* W1t = xb  + (size_t)N_NODES * IN_DIM;      // [256][128]
    __bf16* W2t = W1t + IN_DIM * HID_DIM;              // [256][256]
    __bf16* Wot = W2t + HID_DIM * HID_DIM;             // [128][256]
    unsigned* pairBuf = (unsigned*)(Wot + HID_DIM * OUT_DIM);  // [NB*BCAP]
    int* cursor = (int*)(pairBuf + (size_t)NB * BCAP);         // [NB]

    hipMemsetAsync(d_out, 0, (size_t)N_GRAPHS * OUT_DIM * sizeof(float), stream);
    hipMemsetAsync(cursor, 0, NB * sizeof(int), stream);

    // ---- converts ----
    {
        int n4 = N_NODES * IN_DIM / 4;
        convert_x_kernel<<<(n4 + 255) / 256, 256, 0, stream>>>((const float4*)x, (bf16x4*)xb, n4);
    }
    convert_transpose_kernel<<<(IN_DIM * HID_DIM + 255) / 256, 256, 0, stream>>>(W1, W1t, IN_DIM, HID_DIM);
    convert_transpose_kernel<<<(HID_DIM * HID_DIM + 255) / 256, 256, 0, stream>>>(W2, W2t, HID_DIM, HID_DIM);
    convert_transpose_kernel<<<(HID_DIM * OUT_DIM + 255) / 256, 256, 0, stream>>>(Wo, Wot, HID_DIM, OUT_DIM);

    // ---- bucket edges + fused aggregate ----
    bucket_kernel<<<(N_EDGES + 255) / 256, 256, 0, stream>>>(ei, cursor, pairBuf);
    agg_kernel<<<NB, 256, 0, stream>>>(x, xb, cursor, pairBuf, A);

    // ---- MLP (weight-stationary bf16 MFMA) ----
    const int NSTRIP_BLK = M_PAD / 32 / 4;  // 782
    {
        dim3 grid(NSTRIP_BLK, HID_DIM / 128);
        gemm_ws<IN_DIM, HID_DIM, true, false><<<grid, 256, 0, stream>>>(A, W1t, b1, H1, nullptr);
    }
    {
        dim3 grid(NSTRIP_BLK, HID_DIM / 128);
        gemm_ws<HID_DIM, HID_DIM, true, false><<<grid, 256, 0, stream>>>(H1, W2t, b2, H2, nullptr);
    }
    {
        dim3 grid(NSTRIP_BLK, OUT_DIM / 128);
        gemm_ws<HID_DIM, OUT_DIM, false, true><<<grid, 256, 0, stream>>>(H2, Wot, bo, out, bi);
    }
}

// Round 6
// 406.063 us; speedup vs baseline: 4.8960x; 4.8960x over previous
//
#include <hip/hip_runtime.h>

#define N_NODES  100000
#define M_PAD    100096   // multiple of 128
#define N_EDGES  1600000
#define N_GRAPHS 512
#define IN_DIM   128
#define HID_DIM  256
#define OUT_DIM  128

#define NB       782      // buckets of 128 nodes
#define BCAP     3072     // mean 2048, +22 sigma headroom
#define BKB      196      // bucket_v2 blocks
#define CHUNK    8192     // edges per bucket_v2 block

typedef __bf16 bf16x8 __attribute__((ext_vector_type(8)));
typedef __bf16 bf16x4 __attribute__((ext_vector_type(4)));
typedef __bf16 bf16x2 __attribute__((ext_vector_type(2)));
typedef float  f32x4  __attribute__((ext_vector_type(4)));

// ---------------- x -> bf16 convert ----------------
__global__ __launch_bounds__(256) void convert_x_kernel(const float4* __restrict__ x4,
                                                        bf16x4* __restrict__ xb4, int n4) {
    int i = blockIdx.x * blockDim.x + threadIdx.x;
    if (i < n4) {
        float4 v = x4[i];
        bf16x4 h;
        h.x = (__bf16)v.x; h.y = (__bf16)v.y; h.z = (__bf16)v.z; h.w = (__bf16)v.w;
        xb4[i] = h;
    }
}

// ---------------- weight convert + transpose: Wt[n][k] = bf16(W[k][n]) ----------------
__global__ __launch_bounds__(256) void convert_transpose_kernel(const float* __restrict__ W,
                                                                __bf16* __restrict__ Wt,
                                                                int K, int N) {
    int i = blockIdx.x * blockDim.x + threadIdx.x;
    if (i < K * N) {
        int k = i / N, n = i % N;
        Wt[(size_t)n * K + k] = (__bf16)W[i];
    }
}

// ---------------- bucket_v2: LDS-staged edge binning (low-contention cursors) ----------------
// Packs (src | dstLocal<<17) into per-bucket regions of pairBuf.
__global__ __launch_bounds__(256) void bucket_v2_kernel(const int* __restrict__ ei,
                                                        int* __restrict__ gcursor,
                                                        unsigned* __restrict__ pairBuf) {
    __shared__ int lcnt[NB];
    __shared__ int lbase[NB];
    const int tid = threadIdx.x;
    const int e0 = blockIdx.x * CHUNK;

    for (int b = tid; b < NB; b += 256) lcnt[b] = 0;
    __syncthreads();

    // phase 1: local histogram by bucket
    for (int i = tid; i < CHUNK; i += 256) {
        int e = e0 + i;
        if (e < N_EDGES) atomicAdd(&lcnt[ei[N_EDGES + e] >> 7], 1);
    }
    __syncthreads();

    // phase 2: reserve one contiguous run per bucket (1 global atomic per bucket per block)
    for (int b = tid; b < NB; b += 256) {
        int c = lcnt[b];
        lbase[b] = c ? atomicAdd(&gcursor[b], c) : 0;
        lcnt[b] = 0;   // becomes local slot counter
    }
    __syncthreads();

    // phase 3: dense scatter into reserved runs
    for (int i = tid; i < CHUNK; i += 256) {
        int e = e0 + i;
        if (e < N_EDGES) {
            int s = ei[e];
            int d = ei[N_EDGES + e];
            int b = d >> 7;
            int pos = lbase[b] + atomicAdd(&lcnt[b], 1);
            if (pos < BCAP)
                pairBuf[(size_t)b * BCAP + pos] = (unsigned)s | ((unsigned)(d & 127) << 17);
        }
    }
}

// ---------------- exclusive scan over NB bucket counts ----------------
__global__ __launch_bounds__(1024) void bucket_scan_kernel(const int* __restrict__ gcursor,
                                                           int* __restrict__ bucketBase) {
    __shared__ int s[1024];
    int t = threadIdx.x;
    int v = (t < NB) ? min(gcursor[t], BCAP) : 0;
    s[t] = v;
    __syncthreads();
    for (int st = 1; st < 1024; st <<= 1) {
        int add = (t >= st) ? s[t - st] : 0;
        __syncthreads();
        s[t] += add;
        __syncthreads();
    }
    if (t < NB) bucketBase[t] = s[t] - v;  // exclusive
}

// ---------------- passB: per-bucket CSR build, all traffic L2-local ----------------
// Emits nbr (CSR adjacency), offsets[node], deg[node].
__global__ __launch_bounds__(256) void passB_kernel(const unsigned* __restrict__ pairBuf,
                                                    const int* __restrict__ gcursor,
                                                    const int* __restrict__ bucketBase,
                                                    int* __restrict__ nbr,
                                                    int* __restrict__ offsets,
                                                    int* __restrict__ deg) {
    __shared__ int lcnt[128];
    __shared__ int loffs[128];
    __shared__ int lcur[128];
    const int b = blockIdx.x;
    const int tid = threadIdx.x;
    const int node0 = b << 7;
    const int cnt = min(gcursor[b], BCAP);
    const int base = bucketBase[b];
    const unsigned* pb = pairBuf + (size_t)b * BCAP;

    if (tid < 128) { lcnt[tid] = 0; lcur[tid] = 0; }
    __syncthreads();

    // phase 1: per-node counts within bucket
    for (int i = tid; i < cnt; i += 256)
        atomicAdd(&lcnt[pb[i] >> 17], 1);
    __syncthreads();

    // inclusive Hillis-Steele scan over 128 counters
    if (tid < 128) loffs[tid] = lcnt[tid];
    __syncthreads();
    for (int st = 1; st < 128; st <<= 1) {
        int add = (tid < 128 && tid >= st) ? loffs[tid - st] : 0;
        __syncthreads();
        if (tid < 128) loffs[tid] += add;
        __syncthreads();
    }
    // convert to exclusive + emit deg/offsets
    int excl = 0;
    if (tid < 128) {
        excl = loffs[tid] - lcnt[tid];
        int node = node0 + tid;
        if (node < N_NODES) {
            deg[node] = lcnt[tid];
            offsets[node] = base + excl;
        }
    }
    __syncthreads();
    if (tid < 128) loffs[tid] = excl;
    __syncthreads();

    // phase 2: scatter src into exact CSR position (8 KB window -> L2-local)
    for (int i = tid; i < cnt; i += 256) {
        unsigned u = pb[i];
        int dl = u >> 17;
        int slot = atomicAdd(&lcur[dl], 1);
        nbr[base + loffs[dl] + slot] = (int)(u & 0x1FFFF);
    }
}

// ---------------- gather aggregate: A[v] = bf16( xb[v] + sum xb[nbr] ), fp32 acc ----------------
__global__ __launch_bounds__(256) void aggregate_kernel(const __bf16* __restrict__ xb,
                                                        const int* __restrict__ offsets,
                                                        const int* __restrict__ deg,
                                                        const int* __restrict__ nbr,
                                                        __bf16* __restrict__ A) {
    int v = blockIdx.x * 4 + (threadIdx.x >> 6);
    v = __builtin_amdgcn_readfirstlane(v);
    int lane = threadIdx.x & 63;
    if (v >= N_NODES) return;
    int off = offsets[v];
    int len = deg[v];
    const int c0 = lane * 2;
    bf16x2 self = *(const bf16x2*)(xb + (size_t)v * IN_DIM + c0);
    float ax = (float)self.x, ay = (float)self.y;
    int i = 0;
    for (; i + 4 <= len; i += 4) {
        int s0 = nbr[off + i + 0];
        int s1 = nbr[off + i + 1];
        int s2 = nbr[off + i + 2];
        int s3 = nbr[off + i + 3];
        bf16x2 v0 = *(const bf16x2*)(xb + (size_t)s0 * IN_DIM + c0);
        bf16x2 v1 = *(const bf16x2*)(xb + (size_t)s1 * IN_DIM + c0);
        bf16x2 v2 = *(const bf16x2*)(xb + (size_t)s2 * IN_DIM + c0);
        bf16x2 v3 = *(const bf16x2*)(xb + (size_t)s3 * IN_DIM + c0);
        ax += (float)v0.x + (float)v1.x + (float)v2.x + (float)v3.x;
        ay += (float)v0.y + (float)v1.y + (float)v2.y + (float)v3.y;
    }
    for (; i < len; ++i) {
        int s = nbr[off + i];
        bf16x2 vv = *(const bf16x2*)(xb + (size_t)s * IN_DIM + c0);
        ax += (float)vv.x;
        ay += (float)vv.y;
    }
    bf16x2 h;
    h.x = (__bf16)ax;
    h.y = (__bf16)ay;
    *(bf16x2*)(A + (size_t)v * IN_DIM + c0) = h;
}

// ---------------- weight-stationary bf16 MFMA GEMM ----------------
template <int K, int N, bool RELU, bool POOL>
__global__ __launch_bounds__(256) void gemm_ws(const __bf16* __restrict__ A,
                                               const __bf16* __restrict__ Bt,
                                               const float* __restrict__ bias,
                                               void* __restrict__ C,
                                               const int* __restrict__ batch) {
    constexpr int KS = K / 32;
    constexpr int P  = 8 * KS;
    __shared__ __bf16 Bs[P * 64 * 8];

    const int tid  = threadIdx.x;
    const int wave = tid >> 6;
    const int lane = tid & 63;
    const int quad = lane >> 4, l16 = lane & 15;
    const int colbase = blockIdx.y * 128;

    for (int p = wave; p < P; p += 4) {
        int t = p / KS, s = p % KS;
        bf16x8 w = *(const bf16x8*)(Bt + (size_t)(colbase + t * 16 + l16) * K + s * 32 + quad * 8);
        *(bf16x8*)(Bs + ((size_t)p * 64 + lane) * 8) = w;
    }
    __syncthreads();

    const int strip = blockIdx.x * 4 + wave;
    const int r0 = strip * 32;

    bf16x8 a[2][KS];
    #pragma unroll
    for (int i = 0; i < 2; ++i)
        #pragma unroll
        for (int s = 0; s < KS; ++s)
            a[i][s] = *(const bf16x8*)(A + (size_t)(r0 + i * 16 + l16) * K + s * 32 + quad * 8);

    f32x4 acc[2][8] = {};
    #pragma unroll
    for (int s = 0; s < KS; ++s)
        #pragma unroll
        for (int t = 0; t < 8; ++t) {
            bf16x8 bfrag = *(const bf16x8*)(Bs + ((size_t)(t * KS + s) * 64 + lane) * 8);
            acc[0][t] = __builtin_amdgcn_mfma_f32_16x16x32_bf16(a[0][s], bfrag, acc[0][t], 0, 0, 0);
            acc[1][t] = __builtin_amdgcn_mfma_f32_16x16x32_bf16(a[1][s], bfrag, acc[1][t], 0, 0, 0);
        }

    if (!POOL) {
        #pragma unroll
        for (int i = 0; i < 2; ++i)
            #pragma unroll
            for (int rr = 0; rr < 4; ++rr) {
                size_t m = (size_t)r0 + i * 16 + quad * 4 + rr;
                #pragma unroll
                for (int t = 0; t < 8; ++t) {
                    int c = colbase + t * 16 + l16;
                    float v = acc[i][t][rr] + bias[c];
                    if (RELU) v = fmaxf(v, 0.f);
                    ((__bf16*)C)[m * N + c] = (__bf16)v;
                }
            }
    } else {
        float* out = (float*)C;
        int gfirst = (r0 < N_NODES) ? batch[r0] : -2;
        int glast  = (r0 + 31 < N_NODES) ? batch[r0 + 31] : -1;
        if (gfirst == glast) {
            #pragma unroll
            for (int t = 0; t < 8; ++t) {
                float sum = 0.f;
                #pragma unroll
                for (int i = 0; i < 2; ++i)
                    #pragma unroll
                    for (int rr = 0; rr < 4; ++rr) sum += acc[i][t][rr];
                sum += __shfl_xor(sum, 16, 64);
                sum += __shfl_xor(sum, 32, 64);
                if (quad == 0) {
                    int c = colbase + t * 16 + l16;
                    atomicAdd(out + (size_t)gfirst * N + c, sum + 32.f * bias[c]);
                }
            }
        } else {
            #pragma unroll
            for (int i = 0; i < 2; ++i)
                #pragma unroll
                for (int rr = 0; rr < 4; ++rr) {
                    int m = r0 + i * 16 + quad * 4 + rr;
                    if (m < N_NODES) {
                        int g = batch[m];
                        #pragma unroll
                        for (int t = 0; t < 8; ++t) {
                            int c = colbase + t * 16 + l16;
                            atomicAdd(out + (size_t)g * N + c, acc[i][t][rr] + bias[c]);
                        }
                    }
                }
        }
    }
}

extern "C" void kernel_launch(void* const* d_in, const int* in_sizes, int n_in,
                              void* d_out, int out_size, void* d_ws, size_t ws_size,
                              hipStream_t stream) {
    const float* x  = (const float*)d_in[0];
    const int*   ei = (const int*)d_in[1];
    const int*   bi = (const int*)d_in[2];
    const float* W1 = (const float*)d_in[3];
    const float* b1 = (const float*)d_in[4];
    const float* W2 = (const float*)d_in[5];
    const float* b2 = (const float*)d_in[6];
    const float* Wo = (const float*)d_in[7];
    const float* bo = (const float*)d_in[8];
    float* out = (float*)d_out;

    __bf16* A   = (__bf16*)d_ws;                       // [M_PAD][128]   25.6 MB
    __bf16* H1  = A   + (size_t)M_PAD * IN_DIM;        // [M_PAD][256]   51.2 MB
    __bf16* H2  = H1  + (size_t)M_PAD * HID_DIM;       // [M_PAD][256]   51.2 MB
    __bf16* xb  = H2  + (size_t)M_PAD * HID_DIM;       // [N_NODES][128] 25.6 MB
    __bf16* W1t = xb  + (size_t)N_NODES * IN_DIM;
    __bf16* W2t = W1t + IN_DIM * HID_DIM;
    __bf16* Wot = W2t + HID_DIM * HID_DIM;
    unsigned* pairBuf  = (unsigned*)(Wot + HID_DIM * OUT_DIM);   // 9.6 MB
    int* nbr        = (int*)(pairBuf + (size_t)NB * BCAP);       // 6.4 MB
    int* offsets    = nbr + N_EDGES;
    int* deg        = offsets + N_NODES;
    int* gcursor    = deg + N_NODES;
    int* bucketBase = gcursor + NB;

    hipMemsetAsync(d_out, 0, (size_t)N_GRAPHS * OUT_DIM * sizeof(float), stream);
    hipMemsetAsync(gcursor, 0, NB * sizeof(int), stream);

    // ---- converts ----
    {
        int n4 = N_NODES * IN_DIM / 4;
        convert_x_kernel<<<(n4 + 255) / 256, 256, 0, stream>>>((const float4*)x, (bf16x4*)xb, n4);
    }
    convert_transpose_kernel<<<(IN_DIM * HID_DIM + 255) / 256, 256, 0, stream>>>(W1, W1t, IN_DIM, HID_DIM);
    convert_transpose_kernel<<<(HID_DIM * HID_DIM + 255) / 256, 256, 0, stream>>>(W2, W2t, HID_DIM, HID_DIM);
    convert_transpose_kernel<<<(HID_DIM * OUT_DIM + 255) / 256, 256, 0, stream>>>(Wo, Wot, HID_DIM, OUT_DIM);

    // ---- CSR build: bin -> scan -> bucket-local scatter ----
    bucket_v2_kernel<<<BKB, 256, 0, stream>>>(ei, gcursor, pairBuf);
    bucket_scan_kernel<<<1, 1024, 0, stream>>>(gcursor, bucketBase);
    passB_kernel<<<NB, 256, 0, stream>>>(pairBuf, gcursor, bucketBase, nbr, offsets, deg);

    // ---- aggregate: A = bf16(xb + gather-sum) ----
    aggregate_kernel<<<(N_NODES + 3) / 4, 256, 0, stream>>>(xb, offsets, deg, nbr, A);

    // ---- MLP (weight-stationary bf16 MFMA) ----
    const int NSTRIP_BLK = M_PAD / 32 / 4;  // 782
    {
        dim3 grid(NSTRIP_BLK, HID_DIM / 128);
        gemm_ws<IN_DIM, HID_DIM, true, false><<<grid, 256, 0, stream>>>(A, W1t, b1, H1, nullptr);
    }
    {
        dim3 grid(NSTRIP_BLK, HID_DIM / 128);
        gemm_ws<HID_DIM, HID_DIM, true, false><<<grid, 256, 0, stream>>>(H1, W2t, b2, H2, nullptr);
    }
    {
        dim3 grid(NSTRIP_BLK, OUT_DIM / 128);
        gemm_ws<HID_DIM, OUT_DIM, false, true><<<grid, 256, 0, stream>>>(H2, Wot, bo, out, bi);
    }
}

// Round 7
// 386.201 us; speedup vs baseline: 5.1478x; 1.0514x over previous
//
#include <hip/hip_runtime.h>

#define N_NODES  100000
#define M_PAD    100096   // multiple of 128
#define N_EDGES  1600000
#define N_GRAPHS 512
#define IN_DIM   128
#define HID_DIM  256
#define OUT_DIM  128

#define NB       782      // buckets of 128 nodes
#define BCAP     3072     // mean 2048, +22 sigma headroom
#define BKB      196      // bucket_v2 blocks
#define CHUNK    8192     // edges per bucket_v2 block

typedef __bf16 bf16x8 __attribute__((ext_vector_type(8)));
typedef __bf16 bf16x4 __attribute__((ext_vector_type(4)));
typedef __bf16 bf16x2 __attribute__((ext_vector_type(2)));
typedef float  f32x4  __attribute__((ext_vector_type(4)));

// ---------------- x -> bf16 convert ----------------
__global__ __launch_bounds__(256) void convert_x_kernel(const float4* __restrict__ x4,
                                                        bf16x4* __restrict__ xb4, int n4) {
    int i = blockIdx.x * blockDim.x + threadIdx.x;
    if (i < n4) {
        float4 v = x4[i];
        bf16x4 h;
        h.x = (__bf16)v.x; h.y = (__bf16)v.y; h.z = (__bf16)v.z; h.w = (__bf16)v.w;
        xb4[i] = h;
    }
}

// ---------------- weight convert + transpose: Wt[n][k] = bf16(W[k][n]) ----------------
__global__ __launch_bounds__(256) void convert_transpose_kernel(const float* __restrict__ W,
                                                                __bf16* __restrict__ Wt,
                                                                int K, int N) {
    int i = blockIdx.x * blockDim.x + threadIdx.x;
    if (i < K * N) {
        int k = i / N, n = i % N;
        Wt[(size_t)n * K + k] = (__bf16)W[i];
    }
}

// ---------------- bucket_v2: LDS-staged edge binning (low-contention cursors) ----------------
__global__ __launch_bounds__(256) void bucket_v2_kernel(const int* __restrict__ ei,
                                                        int* __restrict__ gcursor,
                                                        unsigned* __restrict__ pairBuf) {
    __shared__ int lcnt[NB];
    __shared__ int lbase[NB];
    const int tid = threadIdx.x;
    const int e0 = blockIdx.x * CHUNK;

    for (int b = tid; b < NB; b += 256) lcnt[b] = 0;
    __syncthreads();

    for (int i = tid; i < CHUNK; i += 256) {
        int e = e0 + i;
        if (e < N_EDGES) atomicAdd(&lcnt[ei[N_EDGES + e] >> 7], 1);
    }
    __syncthreads();

    for (int b = tid; b < NB; b += 256) {
        int c = lcnt[b];
        lbase[b] = c ? atomicAdd(&gcursor[b], c) : 0;
        lcnt[b] = 0;
    }
    __syncthreads();

    for (int i = tid; i < CHUNK; i += 256) {
        int e = e0 + i;
        if (e < N_EDGES) {
            int s = ei[e];
            int d = ei[N_EDGES + e];
            int b = d >> 7;
            int pos = lbase[b] + atomicAdd(&lcnt[b], 1);
            if (pos < BCAP)
                pairBuf[(size_t)b * BCAP + pos] = (unsigned)s | ((unsigned)(d & 127) << 17);
        }
    }
}

// ---------------- exclusive scan over NB bucket counts ----------------
__global__ __launch_bounds__(1024) void bucket_scan_kernel(const int* __restrict__ gcursor,
                                                           int* __restrict__ bucketBase) {
    __shared__ int s[1024];
    int t = threadIdx.x;
    int v = (t < NB) ? min(gcursor[t], BCAP) : 0;
    s[t] = v;
    __syncthreads();
    for (int st = 1; st < 1024; st <<= 1) {
        int add = (t >= st) ? s[t - st] : 0;
        __syncthreads();
        s[t] += add;
        __syncthreads();
    }
    if (t < NB) bucketBase[t] = s[t] - v;
}

// ---------------- passB: per-bucket CSR build, all traffic L2-local ----------------
__global__ __launch_bounds__(256) void passB_kernel(const unsigned* __restrict__ pairBuf,
                                                    const int* __restrict__ gcursor,
                                                    const int* __restrict__ bucketBase,
                                                    int* __restrict__ nbr,
                                                    int* __restrict__ offsets,
                                                    int* __restrict__ deg) {
    __shared__ int lcnt[128];
    __shared__ int loffs[128];
    __shared__ int lcur[128];
    const int b = blockIdx.x;
    const int tid = threadIdx.x;
    const int node0 = b << 7;
    const int cnt = min(gcursor[b], BCAP);
    const int base = bucketBase[b];
    const unsigned* pb = pairBuf + (size_t)b * BCAP;

    if (tid < 128) { lcnt[tid] = 0; lcur[tid] = 0; }
    __syncthreads();

    for (int i = tid; i < cnt; i += 256)
        atomicAdd(&lcnt[pb[i] >> 17], 1);
    __syncthreads();

    if (tid < 128) loffs[tid] = lcnt[tid];
    __syncthreads();
    for (int st = 1; st < 128; st <<= 1) {
        int add = (tid < 128 && tid >= st) ? loffs[tid - st] : 0;
        __syncthreads();
        if (tid < 128) loffs[tid] += add;
        __syncthreads();
    }
    int excl = 0;
    if (tid < 128) {
        excl = loffs[tid] - lcnt[tid];
        int node = node0 + tid;
        if (node < N_NODES) {
            deg[node] = lcnt[tid];
            offsets[node] = base + excl;
        }
    }
    __syncthreads();
    if (tid < 128) loffs[tid] = excl;
    __syncthreads();

    for (int i = tid; i < cnt; i += 256) {
        unsigned u = pb[i];
        int dl = u >> 17;
        int slot = atomicAdd(&lcur[dl], 1);
        nbr[base + loffs[dl] + slot] = (int)(u & 0x1FFFF);
    }
}

// ---------------- gather aggregate: A[v] = bf16( xb[v] + sum xb[nbr] ), fp32 acc ----------------
__global__ __launch_bounds__(256) void aggregate_kernel(const __bf16* __restrict__ xb,
                                                        const int* __restrict__ offsets,
                                                        const int* __restrict__ deg,
                                                        const int* __restrict__ nbr,
                                                        __bf16* __restrict__ A) {
    int v = blockIdx.x * 4 + (threadIdx.x >> 6);
    v = __builtin_amdgcn_readfirstlane(v);
    int lane = threadIdx.x & 63;
    if (v >= N_NODES) return;
    int off = offsets[v];
    int len = deg[v];
    const int c0 = lane * 2;
    bf16x2 self = *(const bf16x2*)(xb + (size_t)v * IN_DIM + c0);
    float ax = (float)self.x, ay = (float)self.y;
    int i = 0;
    for (; i + 8 <= len; i += 8) {
        int s0 = nbr[off + i + 0];
        int s1 = nbr[off + i + 1];
        int s2 = nbr[off + i + 2];
        int s3 = nbr[off + i + 3];
        int s4 = nbr[off + i + 4];
        int s5 = nbr[off + i + 5];
        int s6 = nbr[off + i + 6];
        int s7 = nbr[off + i + 7];
        bf16x2 v0 = *(const bf16x2*)(xb + (size_t)s0 * IN_DIM + c0);
        bf16x2 v1 = *(const bf16x2*)(xb + (size_t)s1 * IN_DIM + c0);
        bf16x2 v2 = *(const bf16x2*)(xb + (size_t)s2 * IN_DIM + c0);
        bf16x2 v3 = *(const bf16x2*)(xb + (size_t)s3 * IN_DIM + c0);
        bf16x2 v4 = *(const bf16x2*)(xb + (size_t)s4 * IN_DIM + c0);
        bf16x2 v5 = *(const bf16x2*)(xb + (size_t)s5 * IN_DIM + c0);
        bf16x2 v6 = *(const bf16x2*)(xb + (size_t)s6 * IN_DIM + c0);
        bf16x2 v7 = *(const bf16x2*)(xb + (size_t)s7 * IN_DIM + c0);
        ax += (float)v0.x + (float)v1.x + (float)v2.x + (float)v3.x
            + (float)v4.x + (float)v5.x + (float)v6.x + (float)v7.x;
        ay += (float)v0.y + (float)v1.y + (float)v2.y + (float)v3.y
            + (float)v4.y + (float)v5.y + (float)v6.y + (float)v7.y;
    }
    for (; i < len; ++i) {
        int s = nbr[off + i];
        bf16x2 vv = *(const bf16x2*)(xb + (size_t)s * IN_DIM + c0);
        ax += (float)vv.x;
        ay += (float)vv.y;
    }
    bf16x2 h;
    h.x = (__bf16)ax;
    h.y = (__bf16)ay;
    *(bf16x2*)(A + (size_t)v * IN_DIM + c0) = h;
}

// ---------------- weight-stationary bf16 MFMA GEMM, 64-col slab ----------------
// LDS 16 KB (K=128) / 32 KB (K=256) -> 4-5 blocks/CU instead of 2.
template <int K, int N, bool RELU, bool POOL>
__global__ __launch_bounds__(256) void gemm_ws(const __bf16* __restrict__ A,
                                               const __bf16* __restrict__ Bt,
                                               const float* __restrict__ bias,
                                               void* __restrict__ C,
                                               const int* __restrict__ batch) {
    constexpr int KS = K / 32;
    constexpr int P  = 4 * KS;          // 4 n-tiles x KS k-steps
    __shared__ __bf16 Bs[P * 64 * 8];   // P x 1 KB

    const int tid  = threadIdx.x;
    const int wave = tid >> 6;
    const int lane = tid & 63;
    const int quad = lane >> 4, l16 = lane & 15;
    const int colbase = blockIdx.y * 64;

    for (int p = wave; p < P; p += 4) {
        int t = p / KS, s = p % KS;
        bf16x8 w = *(const bf16x8*)(Bt + (size_t)(colbase + t * 16 + l16) * K + s * 32 + quad * 8);
        *(bf16x8*)(Bs + ((size_t)p * 64 + lane) * 8) = w;
    }
    __syncthreads();

    const int strip = blockIdx.x * 4 + wave;
    const int r0 = strip * 32;

    bf16x8 a[2][KS];
    #pragma unroll
    for (int i = 0; i < 2; ++i)
        #pragma unroll
        for (int s = 0; s < KS; ++s)
            a[i][s] = *(const bf16x8*)(A + (size_t)(r0 + i * 16 + l16) * K + s * 32 + quad * 8);

    f32x4 acc[2][4] = {};
    #pragma unroll
    for (int s = 0; s < KS; ++s)
        #pragma unroll
        for (int t = 0; t < 4; ++t) {
            bf16x8 bfrag = *(const bf16x8*)(Bs + ((size_t)(t * KS + s) * 64 + lane) * 8);
            acc[0][t] = __builtin_amdgcn_mfma_f32_16x16x32_bf16(a[0][s], bfrag, acc[0][t], 0, 0, 0);
            acc[1][t] = __builtin_amdgcn_mfma_f32_16x16x32_bf16(a[1][s], bfrag, acc[1][t], 0, 0, 0);
        }

    if (!POOL) {
        #pragma unroll
        for (int i = 0; i < 2; ++i)
            #pragma unroll
            for (int rr = 0; rr < 4; ++rr) {
                size_t m = (size_t)r0 + i * 16 + quad * 4 + rr;
                #pragma unroll
                for (int t = 0; t < 4; ++t) {
                    int c = colbase + t * 16 + l16;
                    float v = acc[i][t][rr] + bias[c];
                    if (RELU) v = fmaxf(v, 0.f);
                    ((__bf16*)C)[m * N + c] = (__bf16)v;
                }
            }
    } else {
        float* out = (float*)C;
        int gfirst = (r0 < N_NODES) ? batch[r0] : -2;
        int glast  = (r0 + 31 < N_NODES) ? batch[r0 + 31] : -1;
        if (gfirst == glast) {
            #pragma unroll
            for (int t = 0; t < 4; ++t) {
                float sum = 0.f;
                #pragma unroll
                for (int i = 0; i < 2; ++i)
                    #pragma unroll
                    for (int rr = 0; rr < 4; ++rr) sum += acc[i][t][rr];
                sum += __shfl_xor(sum, 16, 64);
                sum += __shfl_xor(sum, 32, 64);
                if (quad == 0) {
                    int c = colbase + t * 16 + l16;
                    atomicAdd(out + (size_t)gfirst * N + c, sum + 32.f * bias[c]);
                }
            }
        } else {
            #pragma unroll
            for (int i = 0; i < 2; ++i)
                #pragma unroll
                for (int rr = 0; rr < 4; ++rr) {
                    int m = r0 + i * 16 + quad * 4 + rr;
                    if (m < N_NODES) {
                        int g = batch[m];
                        #pragma unroll
                        for (int t = 0; t < 4; ++t) {
                            int c = colbase + t * 16 + l16;
                            atomicAdd(out + (size_t)g * N + c, acc[i][t][rr] + bias[c]);
                        }
                    }
                }
        }
    }
}

extern "C" void kernel_launch(void* const* d_in, const int* in_sizes, int n_in,
                              void* d_out, int out_size, void* d_ws, size_t ws_size,
                              hipStream_t stream) {
    const float* x  = (const float*)d_in[0];
    const int*   ei = (const int*)d_in[1];
    const int*   bi = (const int*)d_in[2];
    const float* W1 = (const float*)d_in[3];
    const float* b1 = (const float*)d_in[4];
    const float* W2 = (const float*)d_in[5];
    const float* b2 = (const float*)d_in[6];
    const float* Wo = (const float*)d_in[7];
    const float* bo = (const float*)d_in[8];
    float* out = (float*)d_out;

    __bf16* A   = (__bf16*)d_ws;                       // [M_PAD][128]
    __bf16* H1  = A   + (size_t)M_PAD * IN_DIM;        // [M_PAD][256]
    __bf16* H2  = H1  + (size_t)M_PAD * HID_DIM;       // [M_PAD][256]
    __bf16* xb  = H2  + (size_t)M_PAD * HID_DIM;       // [N_NODES][128]
    __bf16* W1t = xb  + (size_t)N_NODES * IN_DIM;
    __bf16* W2t = W1t + IN_DIM * HID_DIM;
    __bf16* Wot = W2t + HID_DIM * HID_DIM;
    unsigned* pairBuf  = (unsigned*)(Wot + HID_DIM * OUT_DIM);
    int* nbr        = (int*)(pairBuf + (size_t)NB * BCAP);
    int* offsets    = nbr + N_EDGES;
    int* deg        = offsets + N_NODES;
    int* gcursor    = deg + N_NODES;
    int* bucketBase = gcursor + NB;

    hipMemsetAsync(d_out, 0, (size_t)N_GRAPHS * OUT_DIM * sizeof(float), stream);
    hipMemsetAsync(gcursor, 0, NB * sizeof(int), stream);

    // ---- converts ----
    {
        int n4 = N_NODES * IN_DIM / 4;
        convert_x_kernel<<<(n4 + 255) / 256, 256, 0, stream>>>((const float4*)x, (bf16x4*)xb, n4);
    }
    convert_transpose_kernel<<<(IN_DIM * HID_DIM + 255) / 256, 256, 0, stream>>>(W1, W1t, IN_DIM, HID_DIM);
    convert_transpose_kernel<<<(HID_DIM * HID_DIM + 255) / 256, 256, 0, stream>>>(W2, W2t, HID_DIM, HID_DIM);
    convert_transpose_kernel<<<(HID_DIM * OUT_DIM + 255) / 256, 256, 0, stream>>>(Wo, Wot, HID_DIM, OUT_DIM);

    // ---- CSR build ----
    bucket_v2_kernel<<<BKB, 256, 0, stream>>>(ei, gcursor, pairBuf);
    bucket_scan_kernel<<<1, 1024, 0, stream>>>(gcursor, bucketBase);
    passB_kernel<<<NB, 256, 0, stream>>>(pairBuf, gcursor, bucketBase, nbr, offsets, deg);

    // ---- aggregate ----
    aggregate_kernel<<<(N_NODES + 3) / 4, 256, 0, stream>>>(xb, offsets, deg, nbr, A);

    // ---- MLP (weight-stationary bf16 MFMA, 64-col slabs) ----
    const int NSTRIP_BLK = M_PAD / 32 / 4;  // 782
    {
        dim3 grid(NSTRIP_BLK, HID_DIM / 64);
        gemm_ws<IN_DIM, HID_DIM, true, false><<<grid, 256, 0, stream>>>(A, W1t, b1, H1, nullptr);
    }
    {
        dim3 grid(NSTRIP_BLK, HID_DIM / 64);
        gemm_ws<HID_DIM, HID_DIM, true, false><<<grid, 256, 0, stream>>>(H1, W2t, b2, H2, nullptr);
    }
    {
        dim3 grid(NSTRIP_BLK, OUT_DIM / 64);
        gemm_ws<HID_DIM, OUT_DIM, false, true><<<grid, 256, 0, stream>>>(H2, Wot, bo, out, bi);
    }
}

// Round 8
// 377.997 us; speedup vs baseline: 5.2596x; 1.0217x over previous
//
#include <hip/hip_runtime.h>

#define N_NODES  100000
#define M_PAD    100096   // multiple of 128
#define N_EDGES  1600000
#define N_GRAPHS 512
#define IN_DIM   128
#define HID_DIM  256
#define OUT_DIM  128

#define NB       782      // buckets of 128 nodes
#define BCAP     3072     // mean 2048, +22 sigma headroom
#define BKB      196      // bucket_v2 blocks
#define CHUNK    8192     // edges per bucket_v2 block

typedef __bf16 bf16x8 __attribute__((ext_vector_type(8)));
typedef __bf16 bf16x4 __attribute__((ext_vector_type(4)));
typedef __bf16 bf16x2 __attribute__((ext_vector_type(2)));
typedef float  f32x4  __attribute__((ext_vector_type(4)));

// ---------------- x -> bf16 convert ----------------
__global__ __launch_bounds__(256) void convert_x_kernel(const float4* __restrict__ x4,
                                                        bf16x4* __restrict__ xb4, int n4) {
    int i = blockIdx.x * blockDim.x + threadIdx.x;
    if (i < n4) {
        float4 v = x4[i];
        bf16x4 h;
        h.x = (__bf16)v.x; h.y = (__bf16)v.y; h.z = (__bf16)v.z; h.w = (__bf16)v.w;
        xb4[i] = h;
    }
}

// ---------------- weight convert + transpose: Wt[n][k] = bf16(W[k][n]) ----------------
__global__ __launch_bounds__(256) void convert_transpose_kernel(const float* __restrict__ W,
                                                                __bf16* __restrict__ Wt,
                                                                int K, int N) {
    int i = blockIdx.x * blockDim.x + threadIdx.x;
    if (i < K * N) {
        int k = i / N, n = i % N;
        Wt[(size_t)n * K + k] = (__bf16)W[i];
    }
}

// ---------------- bucket_v2: LDS-staged edge binning ----------------
__global__ __launch_bounds__(256) void bucket_v2_kernel(const int* __restrict__ ei,
                                                        int* __restrict__ gcursor,
                                                        unsigned* __restrict__ pairBuf) {
    __shared__ int lcnt[NB];
    __shared__ int lbase[NB];
    const int tid = threadIdx.x;
    const int e0 = blockIdx.x * CHUNK;

    for (int b = tid; b < NB; b += 256) lcnt[b] = 0;
    __syncthreads();

    for (int i = tid; i < CHUNK; i += 256) {
        int e = e0 + i;
        if (e < N_EDGES) atomicAdd(&lcnt[ei[N_EDGES + e] >> 7], 1);
    }
    __syncthreads();

    for (int b = tid; b < NB; b += 256) {
        int c = lcnt[b];
        lbase[b] = c ? atomicAdd(&gcursor[b], c) : 0;
        lcnt[b] = 0;
    }
    __syncthreads();

    for (int i = tid; i < CHUNK; i += 256) {
        int e = e0 + i;
        if (e < N_EDGES) {
            int s = ei[e];
            int d = ei[N_EDGES + e];
            int b = d >> 7;
            int pos = lbase[b] + atomicAdd(&lcnt[b], 1);
            if (pos < BCAP)
                pairBuf[(size_t)b * BCAP + pos] = (unsigned)s | ((unsigned)(d & 127) << 17);
        }
    }
}

// ---------------- exclusive scan over NB bucket counts ----------------
__global__ __launch_bounds__(1024) void bucket_scan_kernel(const int* __restrict__ gcursor,
                                                           int* __restrict__ bucketBase) {
    __shared__ int s[1024];
    int t = threadIdx.x;
    int v = (t < NB) ? min(gcursor[t], BCAP) : 0;
    s[t] = v;
    __syncthreads();
    for (int st = 1; st < 1024; st <<= 1) {
        int add = (t >= st) ? s[t - st] : 0;
        __syncthreads();
        s[t] += add;
        __syncthreads();
    }
    if (t < NB) bucketBase[t] = s[t] - v;
}

// ---------------- passB: per-bucket CSR build ----------------
__global__ __launch_bounds__(256) void passB_kernel(const unsigned* __restrict__ pairBuf,
                                                    const int* __restrict__ gcursor,
                                                    const int* __restrict__ bucketBase,
                                                    int* __restrict__ nbr,
                                                    int* __restrict__ offsets,
                                                    int* __restrict__ deg) {
    __shared__ int lcnt[128];
    __shared__ int loffs[128];
    __shared__ int lcur[128];
    const int b = blockIdx.x;
    const int tid = threadIdx.x;
    const int node0 = b << 7;
    const int cnt = min(gcursor[b], BCAP);
    const int base = bucketBase[b];
    const unsigned* pb = pairBuf + (size_t)b * BCAP;

    if (tid < 128) { lcnt[tid] = 0; lcur[tid] = 0; }
    __syncthreads();

    for (int i = tid; i < cnt; i += 256)
        atomicAdd(&lcnt[pb[i] >> 17], 1);
    __syncthreads();

    if (tid < 128) loffs[tid] = lcnt[tid];
    __syncthreads();
    for (int st = 1; st < 128; st <<= 1) {
        int add = (tid < 128 && tid >= st) ? loffs[tid - st] : 0;
        __syncthreads();
        if (tid < 128) loffs[tid] += add;
        __syncthreads();
    }
    int excl = 0;
    if (tid < 128) {
        excl = loffs[tid] - lcnt[tid];
        int node = node0 + tid;
        if (node < N_NODES) {
            deg[node] = lcnt[tid];
            offsets[node] = base + excl;
        }
    }
    __syncthreads();
    if (tid < 128) loffs[tid] = excl;
    __syncthreads();

    for (int i = tid; i < cnt; i += 256) {
        unsigned u = pb[i];
        int dl = u >> 17;
        int slot = atomicAdd(&lcur[dl], 1);
        nbr[base + loffs[dl] + slot] = (int)(u & 0x1FFFF);
    }
}

// ---------------- gather aggregate, de-chained ----------------
// nbr ids loaded lane-parallel (one vector load covers 64 edges), broadcast
// via __shfl -> gathers issue without a dependent index load per iteration.
__global__ __launch_bounds__(256) void aggregate_kernel(const __bf16* __restrict__ xb,
                                                        const int* __restrict__ offsets,
                                                        const int* __restrict__ deg,
                                                        const int* __restrict__ nbr,
                                                        __bf16* __restrict__ A) {
    int v = blockIdx.x * 4 + (threadIdx.x >> 6);
    v = __builtin_amdgcn_readfirstlane(v);
    int lane = threadIdx.x & 63;
    if (v >= N_NODES) return;
    int off = offsets[v];
    int len = deg[v];
    const int c0 = lane * 2;
    bf16x2 self = *(const bf16x2*)(xb + (size_t)v * IN_DIM + c0);
    float ax = (float)self.x, ay = (float)self.y;

    // lane-parallel neighbor-id load (clamped address; guarded by lim below)
    int addr = off + lane;
    if (addr > N_EDGES - 1) addr = N_EDGES - 1;
    int myidx = nbr[addr];

    int lim = len < 64 ? len : 64;
    int j = 0;
    for (; j + 8 <= lim; j += 8) {
        int s0 = __shfl(myidx, j + 0, 64);
        int s1 = __shfl(myidx, j + 1, 64);
        int s2 = __shfl(myidx, j + 2, 64);
        int s3 = __shfl(myidx, j + 3, 64);
        int s4 = __shfl(myidx, j + 4, 64);
        int s5 = __shfl(myidx, j + 5, 64);
        int s6 = __shfl(myidx, j + 6, 64);
        int s7 = __shfl(myidx, j + 7, 64);
        bf16x2 v0 = *(const bf16x2*)(xb + (size_t)s0 * IN_DIM + c0);
        bf16x2 v1 = *(const bf16x2*)(xb + (size_t)s1 * IN_DIM + c0);
        bf16x2 v2 = *(const bf16x2*)(xb + (size_t)s2 * IN_DIM + c0);
        bf16x2 v3 = *(const bf16x2*)(xb + (size_t)s3 * IN_DIM + c0);
        bf16x2 v4 = *(const bf16x2*)(xb + (size_t)s4 * IN_DIM + c0);
        bf16x2 v5 = *(const bf16x2*)(xb + (size_t)s5 * IN_DIM + c0);
        bf16x2 v6 = *(const bf16x2*)(xb + (size_t)s6 * IN_DIM + c0);
        bf16x2 v7 = *(const bf16x2*)(xb + (size_t)s7 * IN_DIM + c0);
        ax += (float)v0.x + (float)v1.x + (float)v2.x + (float)v3.x
            + (float)v4.x + (float)v5.x + (float)v6.x + (float)v7.x;
        ay += (float)v0.y + (float)v1.y + (float)v2.y + (float)v3.y
            + (float)v4.y + (float)v5.y + (float)v6.y + (float)v7.y;
    }
    for (; j < lim; ++j) {
        int s = __shfl(myidx, j, 64);
        bf16x2 vv = *(const bf16x2*)(xb + (size_t)s * IN_DIM + c0);
        ax += (float)vv.x;
        ay += (float)vv.y;
    }
    // tail beyond 64 neighbors (vanishingly rare; uniform-load fallback)
    for (; j < len; ++j) {
        int s = nbr[off + j];
        bf16x2 vv = *(const bf16x2*)(xb + (size_t)s * IN_DIM + c0);
        ax += (float)vv.x;
        ay += (float)vv.y;
    }
    bf16x2 h;
    h.x = (__bf16)ax;
    h.y = (__bf16)ay;
    *(bf16x2*)(A + (size_t)v * IN_DIM + c0) = h;
}

// ---------------- weight-stationary bf16 MFMA GEMM, in-kernel slab loop ----------------
// A-fragments loaded ONCE into VGPRs, reused across all N/64 column slabs.
// Weights restaged in LDS per slab (16/32 KB).
template <int K, int N, bool RELU, bool POOL>
__global__ __launch_bounds__(256) void gemm_ws(const __bf16* __restrict__ A,
                                               const __bf16* __restrict__ Bt,
                                               const float* __restrict__ bias,
                                               void* __restrict__ C,
                                               const int* __restrict__ batch) {
    constexpr int KS = K / 32;
    constexpr int P  = 4 * KS;          // 4 n-tiles x KS k-steps per slab
    constexpr int NSLAB = N / 64;
    __shared__ __bf16 Bs[P * 64 * 8];

    const int tid  = threadIdx.x;
    const int wave = tid >> 6;
    const int lane = tid & 63;
    const int quad = lane >> 4, l16 = lane & 15;

    const int strip = blockIdx.x * 4 + wave;
    const int r0 = strip * 32;

    // A-fragments: 2 m-tiles x KS k-steps, loaded once (coalesced dwordx4)
    bf16x8 a[2][KS];
    #pragma unroll
    for (int i = 0; i < 2; ++i)
        #pragma unroll
        for (int s = 0; s < KS; ++s)
            a[i][s] = *(const bf16x8*)(A + (size_t)(r0 + i * 16 + l16) * K + s * 32 + quad * 8);

    int gfirst = -2, glast = -1;
    if (POOL) {
        gfirst = (r0 < N_NODES) ? batch[r0] : -2;
        glast  = (r0 + 31 < N_NODES) ? batch[r0 + 31] : -1;
    }

    for (int slab = 0; slab < NSLAB; ++slab) {
        const int colbase = slab * 64;
        // stage this slab's weights as B-fragments
        for (int p = wave; p < P; p += 4) {
            int t = p / KS, s = p % KS;
            bf16x8 w = *(const bf16x8*)(Bt + (size_t)(colbase + t * 16 + l16) * K + s * 32 + quad * 8);
            *(bf16x8*)(Bs + ((size_t)p * 64 + lane) * 8) = w;
        }
        __syncthreads();

        f32x4 acc[2][4] = {};
        #pragma unroll
        for (int s = 0; s < KS; ++s)
            #pragma unroll
            for (int t = 0; t < 4; ++t) {
                bf16x8 bfrag = *(const bf16x8*)(Bs + ((size_t)(t * KS + s) * 64 + lane) * 8);
                acc[0][t] = __builtin_amdgcn_mfma_f32_16x16x32_bf16(a[0][s], bfrag, acc[0][t], 0, 0, 0);
                acc[1][t] = __builtin_amdgcn_mfma_f32_16x16x32_bf16(a[1][s], bfrag, acc[1][t], 0, 0, 0);
            }
        __syncthreads();   // all ds_reads done before next slab's staging

        if (!POOL) {
            #pragma unroll
            for (int i = 0; i < 2; ++i)
                #pragma unroll
                for (int rr = 0; rr < 4; ++rr) {
                    size_t m = (size_t)r0 + i * 16 + quad * 4 + rr;
                    #pragma unroll
                    for (int t = 0; t < 4; ++t) {
                        int c = colbase + t * 16 + l16;
                        float v = acc[i][t][rr] + bias[c];
                        if (RELU) v = fmaxf(v, 0.f);
                        ((__bf16*)C)[m * N + c] = (__bf16)v;
                    }
                }
        } else {
            float* out = (float*)C;
            if (gfirst == glast) {
                #pragma unroll
                for (int t = 0; t < 4; ++t) {
                    float sum = 0.f;
                    #pragma unroll
                    for (int i = 0; i < 2; ++i)
                        #pragma unroll
                        for (int rr = 0; rr < 4; ++rr) sum += acc[i][t][rr];
                    sum += __shfl_xor(sum, 16, 64);
                    sum += __shfl_xor(sum, 32, 64);
                    if (quad == 0) {
                        int c = colbase + t * 16 + l16;
                        atomicAdd(out + (size_t)gfirst * N + c, sum + 32.f * bias[c]);
                    }
                }
            } else {
                #pragma unroll
                for (int i = 0; i < 2; ++i)
                    #pragma unroll
                    for (int rr = 0; rr < 4; ++rr) {
                        int m = r0 + i * 16 + quad * 4 + rr;
                        if (m < N_NODES) {
                            int g = batch[m];
                            #pragma unroll
                            for (int t = 0; t < 4; ++t) {
                                int c = colbase + t * 16 + l16;
                                atomicAdd(out + (size_t)g * N + c, acc[i][t][rr] + bias[c]);
                            }
                        }
                    }
            }
        }
    }
}

extern "C" void kernel_launch(void* const* d_in, const int* in_sizes, int n_in,
                              void* d_out, int out_size, void* d_ws, size_t ws_size,
                              hipStream_t stream) {
    const float* x  = (const float*)d_in[0];
    const int*   ei = (const int*)d_in[1];
    const int*   bi = (const int*)d_in[2];
    const float* W1 = (const float*)d_in[3];
    const float* b1 = (const float*)d_in[4];
    const float* W2 = (const float*)d_in[5];
    const float* b2 = (const float*)d_in[6];
    const float* Wo = (const float*)d_in[7];
    const float* bo = (const float*)d_in[8];
    float* out = (float*)d_out;

    __bf16* A   = (__bf16*)d_ws;                       // [M_PAD][128]
    __bf16* H1  = A   + (size_t)M_PAD * IN_DIM;        // [M_PAD][256]
    __bf16* H2  = H1  + (size_t)M_PAD * HID_DIM;       // [M_PAD][256]
    __bf16* xb  = H2  + (size_t)M_PAD * HID_DIM;       // [N_NODES][128]
    __bf16* W1t = xb  + (size_t)N_NODES * IN_DIM;
    __bf16* W2t = W1t + IN_DIM * HID_DIM;
    __bf16* Wot = W2t + HID_DIM * HID_DIM;
    unsigned* pairBuf  = (unsigned*)(Wot + HID_DIM * OUT_DIM);
    int* nbr        = (int*)(pairBuf + (size_t)NB * BCAP);
    int* offsets    = nbr + N_EDGES;
    int* deg        = offsets + N_NODES;
    int* gcursor    = deg + N_NODES;
    int* bucketBase = gcursor + NB;

    hipMemsetAsync(d_out, 0, (size_t)N_GRAPHS * OUT_DIM * sizeof(float), stream);
    hipMemsetAsync(gcursor, 0, NB * sizeof(int), stream);

    // ---- converts ----
    {
        int n4 = N_NODES * IN_DIM / 4;
        convert_x_kernel<<<(n4 + 255) / 256, 256, 0, stream>>>((const float4*)x, (bf16x4*)xb, n4);
    }
    convert_transpose_kernel<<<(IN_DIM * HID_DIM + 255) / 256, 256, 0, stream>>>(W1, W1t, IN_DIM, HID_DIM);
    convert_transpose_kernel<<<(HID_DIM * HID_DIM + 255) / 256, 256, 0, stream>>>(W2, W2t, HID_DIM, HID_DIM);
    convert_transpose_kernel<<<(HID_DIM * OUT_DIM + 255) / 256, 256, 0, stream>>>(Wo, Wot, HID_DIM, OUT_DIM);

    // ---- CSR build ----
    bucket_v2_kernel<<<BKB, 256, 0, stream>>>(ei, gcursor, pairBuf);
    bucket_scan_kernel<<<1, 1024, 0, stream>>>(gcursor, bucketBase);
    passB_kernel<<<NB, 256, 0, stream>>>(pairBuf, gcursor, bucketBase, nbr, offsets, deg);

    // ---- aggregate ----
    aggregate_kernel<<<(N_NODES + 3) / 4, 256, 0, stream>>>(xb, offsets, deg, nbr, A);

    // ---- MLP (weight-stationary bf16 MFMA, in-kernel slab loop) ----
    const int NSTRIP_BLK = M_PAD / 32 / 4;  // 782
    gemm_ws<IN_DIM, HID_DIM, true, false><<<NSTRIP_BLK, 256, 0, stream>>>(A, W1t, b1, H1, nullptr);
    gemm_ws<HID_DIM, HID_DIM, true, false><<<NSTRIP_BLK, 256, 0, stream>>>(H1, W2t, b2, H2, nullptr);
    gemm_ws<HID_DIM, OUT_DIM, false, true><<<NSTRIP_BLK, 256, 0, stream>>>(H2, Wot, bo, out, bi);
}

// Round 9
// 364.608 us; speedup vs baseline: 5.4527x; 1.0367x over previous
//
#include <hip/hip_runtime.h>

#define N_NODES  100000
#define M_PAD    100096   // multiple of 128
#define N_EDGES  1600000
#define N_GRAPHS 512
#define IN_DIM   128
#define HID_DIM  256
#define OUT_DIM  128

#define NB       782      // buckets of 128 nodes
#define BCAP     3072     // mean 2048, +22 sigma headroom
#define CHUNK    2048     // edges per bucket_v2 block
#define BKB      ((N_EDGES + CHUNK - 1) / CHUNK)   // 782

typedef __bf16 bf16x8 __attribute__((ext_vector_type(8)));
typedef __bf16 bf16x4 __attribute__((ext_vector_type(4)));
typedef __bf16 bf16x2 __attribute__((ext_vector_type(2)));
typedef float  f32x4  __attribute__((ext_vector_type(4)));

// ---------------- fused init: x->bf16, 3 weight transposes, zero d_out & gcursor ----------------
#define R_X   (N_NODES * IN_DIM / 4)            // 3,200,000 float4 chunks
#define R_W1  (IN_DIM * HID_DIM)                // 32768
#define R_W2  (HID_DIM * HID_DIM)               // 65536
#define R_WO  (HID_DIM * OUT_DIM)               // 32768
#define R_OUT (N_GRAPHS * OUT_DIM / 4)          // 16384 float4
#define R_CUR NB
#define R_TOTAL (R_X + R_W1 + R_W2 + R_WO + R_OUT + R_CUR)

__global__ __launch_bounds__(256) void init_kernel(const float* __restrict__ x,
                                                   const float* __restrict__ W1,
                                                   const float* __restrict__ W2,
                                                   const float* __restrict__ Wo,
                                                   __bf16* __restrict__ xb,
                                                   __bf16* __restrict__ W1t,
                                                   __bf16* __restrict__ W2t,
                                                   __bf16* __restrict__ Wot,
                                                   float* __restrict__ outbuf,
                                                   int* __restrict__ gcursor) {
    long long i = (long long)blockIdx.x * blockDim.x + threadIdx.x;
    if (i < R_X) {
        float4 v = ((const float4*)x)[i];
        bf16x4 h;
        h.x = (__bf16)v.x; h.y = (__bf16)v.y; h.z = (__bf16)v.z; h.w = (__bf16)v.w;
        ((bf16x4*)xb)[i] = h;
        return;
    }
    i -= R_X;
    if (i < R_W1) {  // W1: [128][256] -> W1t[n*128+k]
        int k = (int)i / HID_DIM, n = (int)i % HID_DIM;
        W1t[(size_t)n * IN_DIM + k] = (__bf16)W1[i];
        return;
    }
    i -= R_W1;
    if (i < R_W2) {
        int k = (int)i / HID_DIM, n = (int)i % HID_DIM;
        W2t[(size_t)n * HID_DIM + k] = (__bf16)W2[i];
        return;
    }
    i -= R_W2;
    if (i < R_WO) {
        int k = (int)i / OUT_DIM, n = (int)i % OUT_DIM;
        Wot[(size_t)n * HID_DIM + k] = (__bf16)Wo[i];
        return;
    }
    i -= R_WO;
    if (i < R_OUT) {
        ((float4*)outbuf)[i] = make_float4(0.f, 0.f, 0.f, 0.f);
        return;
    }
    i -= R_OUT;
    if (i < R_CUR) gcursor[i] = 0;
}

// ---------------- bucket_v2: LDS-staged edge binning ----------------
__global__ __launch_bounds__(256) void bucket_v2_kernel(const int* __restrict__ ei,
                                                        int* __restrict__ gcursor,
                                                        unsigned* __restrict__ pairBuf) {
    __shared__ int lcnt[NB];
    __shared__ int lbase[NB];
    const int tid = threadIdx.x;
    const int e0 = blockIdx.x * CHUNK;

    for (int b = tid; b < NB; b += 256) lcnt[b] = 0;
    __syncthreads();

    for (int i = tid; i < CHUNK; i += 256) {
        int e = e0 + i;
        if (e < N_EDGES) atomicAdd(&lcnt[ei[N_EDGES + e] >> 7], 1);
    }
    __syncthreads();

    for (int b = tid; b < NB; b += 256) {
        int c = lcnt[b];
        lbase[b] = c ? atomicAdd(&gcursor[b], c) : 0;
        lcnt[b] = 0;
    }
    __syncthreads();

    for (int i = tid; i < CHUNK; i += 256) {
        int e = e0 + i;
        if (e < N_EDGES) {
            int s = ei[e];
            int d = ei[N_EDGES + e];
            int b = d >> 7;
            int pos = lbase[b] + atomicAdd(&lcnt[b], 1);
            if (pos < BCAP)
                pairBuf[(size_t)b * BCAP + pos] = (unsigned)s | ((unsigned)(d & 127) << 17);
        }
    }
}

// ---------------- passB: per-bucket CSR build (bucket-strided, no global scan) ----------------
__global__ __launch_bounds__(256) void passB_kernel(const unsigned* __restrict__ pairBuf,
                                                    const int* __restrict__ gcursor,
                                                    int* __restrict__ nbr,
                                                    int* __restrict__ offsets,
                                                    int* __restrict__ deg) {
    __shared__ int lcnt[128];
    __shared__ int loffs[128];
    __shared__ int lcur[128];
    const int b = blockIdx.x;
    const int tid = threadIdx.x;
    const int node0 = b << 7;
    const int cnt = min(gcursor[b], BCAP);
    const int base = b * BCAP;          // bucket-strided CSR
    const unsigned* pb = pairBuf + (size_t)b * BCAP;

    if (tid < 128) { lcnt[tid] = 0; lcur[tid] = 0; }
    __syncthreads();

    for (int i = tid; i < cnt; i += 256)
        atomicAdd(&lcnt[pb[i] >> 17], 1);
    __syncthreads();

    if (tid < 128) loffs[tid] = lcnt[tid];
    __syncthreads();
    for (int st = 1; st < 128; st <<= 1) {
        int add = (tid < 128 && tid >= st) ? loffs[tid - st] : 0;
        __syncthreads();
        if (tid < 128) loffs[tid] += add;
        __syncthreads();
    }
    int excl = 0;
    if (tid < 128) {
        excl = loffs[tid] - lcnt[tid];
        int node = node0 + tid;
        if (node < N_NODES) {
            deg[node] = lcnt[tid];
            offsets[node] = base + excl;
        }
    }
    __syncthreads();
    if (tid < 128) loffs[tid] = excl;
    __syncthreads();

    for (int i = tid; i < cnt; i += 256) {
        unsigned u = pb[i];
        int dl = u >> 17;
        int slot = atomicAdd(&lcur[dl], 1);
        nbr[base + loffs[dl] + slot] = (int)(u & 0x1FFFF);
    }
}

// ---------------- gather aggregate (near memory floor; unchanged core) ----------------
__global__ __launch_bounds__(256) void aggregate_kernel(const __bf16* __restrict__ xb,
                                                        const int* __restrict__ offsets,
                                                        const int* __restrict__ deg,
                                                        const int* __restrict__ nbr,
                                                        __bf16* __restrict__ A) {
    int v = blockIdx.x * 4 + (threadIdx.x >> 6);
    v = __builtin_amdgcn_readfirstlane(v);
    int lane = threadIdx.x & 63;
    if (v >= N_NODES) return;
    int off = offsets[v];
    int len = deg[v];
    const int c0 = lane * 2;
    bf16x2 self = *(const bf16x2*)(xb + (size_t)v * IN_DIM + c0);
    float ax = (float)self.x, ay = (float)self.y;

    int addr = off + lane;
    if (addr > NB * BCAP - 1) addr = NB * BCAP - 1;
    int myidx = nbr[addr];

    int lim = len < 64 ? len : 64;
    int j = 0;
    for (; j + 8 <= lim; j += 8) {
        int s0 = __shfl(myidx, j + 0, 64);
        int s1 = __shfl(myidx, j + 1, 64);
        int s2 = __shfl(myidx, j + 2, 64);
        int s3 = __shfl(myidx, j + 3, 64);
        int s4 = __shfl(myidx, j + 4, 64);
        int s5 = __shfl(myidx, j + 5, 64);
        int s6 = __shfl(myidx, j + 6, 64);
        int s7 = __shfl(myidx, j + 7, 64);
        bf16x2 v0 = *(const bf16x2*)(xb + (size_t)s0 * IN_DIM + c0);
        bf16x2 v1 = *(const bf16x2*)(xb + (size_t)s1 * IN_DIM + c0);
        bf16x2 v2 = *(const bf16x2*)(xb + (size_t)s2 * IN_DIM + c0);
        bf16x2 v3 = *(const bf16x2*)(xb + (size_t)s3 * IN_DIM + c0);
        bf16x2 v4 = *(const bf16x2*)(xb + (size_t)s4 * IN_DIM + c0);
        bf16x2 v5 = *(const bf16x2*)(xb + (size_t)s5 * IN_DIM + c0);
        bf16x2 v6 = *(const bf16x2*)(xb + (size_t)s6 * IN_DIM + c0);
        bf16x2 v7 = *(const bf16x2*)(xb + (size_t)s7 * IN_DIM + c0);
        ax += (float)v0.x + (float)v1.x + (float)v2.x + (float)v3.x
            + (float)v4.x + (float)v5.x + (float)v6.x + (float)v7.x;
        ay += (float)v0.y + (float)v1.y + (float)v2.y + (float)v3.y
            + (float)v4.y + (float)v5.y + (float)v6.y + (float)v7.y;
    }
    for (; j < lim; ++j) {
        int s = __shfl(myidx, j, 64);
        bf16x2 vv = *(const bf16x2*)(xb + (size_t)s * IN_DIM + c0);
        ax += (float)vv.x;
        ay += (float)vv.y;
    }
    for (; j < len; ++j) {
        int s = nbr[off + j];
        bf16x2 vv = *(const bf16x2*)(xb + (size_t)s * IN_DIM + c0);
        ax += (float)vv.x;
        ay += (float)vv.y;
    }
    bf16x2 h;
    h.x = (__bf16)ax;
    h.y = (__bf16)ay;
    *(bf16x2*)(A + (size_t)v * IN_DIM + c0) = h;
}

// ---------------- weight-stationary bf16 MFMA GEMM, slab loop + weight prefetch ----------------
// A-frags in VGPRs once; per slab: commit prefetched weights to LDS, prefetch
// next slab during MFMA+epilogue (hides weight-fetch latency).
template <int K, int N, bool RELU, bool POOL>
__global__ __launch_bounds__(256) void gemm_ws(const __bf16* __restrict__ A,
                                               const __bf16* __restrict__ Bt,
                                               const float* __restrict__ bias,
                                               void* __restrict__ C,
                                               const int* __restrict__ batch) {
    constexpr int KS = K / 32;
    constexpr int P  = 4 * KS;          // frags per 64-col slab
    constexpr int NSLAB = N / 64;
    __shared__ __bf16 Bs[P * 64 * 8];

    const int tid  = threadIdx.x;
    const int wave = tid >> 6;
    const int lane = tid & 63;
    const int quad = lane >> 4, l16 = lane & 15;

    const int strip = blockIdx.x * 4 + wave;
    const int r0 = strip * 32;

    // A-fragments: loaded once (coalesced dwordx4)
    bf16x8 a[2][KS];
    #pragma unroll
    for (int i = 0; i < 2; ++i)
        #pragma unroll
        for (int s = 0; s < KS; ++s)
            a[i][s] = *(const bf16x8*)(A + (size_t)(r0 + i * 16 + l16) * K + s * 32 + quad * 8);

    int gfirst = -2, glast = -1;
    if (POOL) {
        gfirst = (r0 < N_NODES) ? batch[r0] : -2;
        glast  = (r0 + 31 < N_NODES) ? batch[r0 + 31] : -1;
    }

    // prefetch slab 0 weights (wave owns frags p = wave + 4q)
    bf16x8 wreg[KS];
    #pragma unroll
    for (int q = 0; q < KS; ++q) {
        int p = wave + 4 * q;
        int t = p / KS, s = p % KS;
        wreg[q] = *(const bf16x8*)(Bt + (size_t)(t * 16 + l16) * K + s * 32 + quad * 8);
    }

    for (int slab = 0; slab < NSLAB; ++slab) {
        const int colbase = slab * 64;
        // commit prefetched weights to LDS
        #pragma unroll
        for (int q = 0; q < KS; ++q) {
            int p = wave + 4 * q;
            *(bf16x8*)(Bs + ((size_t)p * 64 + lane) * 8) = wreg[q];
        }
        __syncthreads();

        // prefetch next slab (overlaps MFMA + epilogue)
        if (slab + 1 < NSLAB) {
            const int colb = (slab + 1) * 64;
            #pragma unroll
            for (int q = 0; q < KS; ++q) {
                int p = wave + 4 * q;
                int t = p / KS, s = p % KS;
                wreg[q] = *(const bf16x8*)(Bt + (size_t)(colb + t * 16 + l16) * K + s * 32 + quad * 8);
            }
        }

        f32x4 acc[2][4] = {};
        #pragma unroll
        for (int s = 0; s < KS; ++s)
            #pragma unroll
            for (int t = 0; t < 4; ++t) {
                bf16x8 bfrag = *(const bf16x8*)(Bs + ((size_t)(t * KS + s) * 64 + lane) * 8);
                acc[0][t] = __builtin_amdgcn_mfma_f32_16x16x32_bf16(a[0][s], bfrag, acc[0][t], 0, 0, 0);
                acc[1][t] = __builtin_amdgcn_mfma_f32_16x16x32_bf16(a[1][s], bfrag, acc[1][t], 0, 0, 0);
            }

        if (!POOL) {
            #pragma unroll
            for (int i = 0; i < 2; ++i)
                #pragma unroll
                for (int rr = 0; rr < 4; ++rr) {
                    size_t m = (size_t)r0 + i * 16 + quad * 4 + rr;
                    #pragma unroll
                    for (int t = 0; t < 4; ++t) {
                        int c = colbase + t * 16 + l16;
                        float v = acc[i][t][rr] + bias[c];
                        if (RELU) v = fmaxf(v, 0.f);
                        ((__bf16*)C)[m * N + c] = (__bf16)v;
                    }
                }
        } else {
            float* out = (float*)C;
            if (gfirst == glast) {
                #pragma unroll
                for (int t = 0; t < 4; ++t) {
                    float sum = 0.f;
                    #pragma unroll
                    for (int i = 0; i < 2; ++i)
                        #pragma unroll
                        for (int rr = 0; rr < 4; ++rr) sum += acc[i][t][rr];
                    sum += __shfl_xor(sum, 16, 64);
                    sum += __shfl_xor(sum, 32, 64);
                    if (quad == 0) {
                        int c = colbase + t * 16 + l16;
                        atomicAdd(out + (size_t)gfirst * N + c, sum + 32.f * bias[c]);
                    }
                }
            } else {
                #pragma unroll
                for (int i = 0; i < 2; ++i)
                    #pragma unroll
                    for (int rr = 0; rr < 4; ++rr) {
                        int m = r0 + i * 16 + quad * 4 + rr;
                        if (m < N_NODES) {
                            int g = batch[m];
                            #pragma unroll
                            for (int t = 0; t < 4; ++t) {
                                int c = colbase + t * 16 + l16;
                                atomicAdd(out + (size_t)g * N + c, acc[i][t][rr] + bias[c]);
                            }
                        }
                    }
            }
        }
        __syncthreads();   // Bs reads done before next slab's commit
    }
}

extern "C" void kernel_launch(void* const* d_in, const int* in_sizes, int n_in,
                              void* d_out, int out_size, void* d_ws, size_t ws_size,
                              hipStream_t stream) {
    const float* x  = (const float*)d_in[0];
    const int*   ei = (const int*)d_in[1];
    const int*   bi = (const int*)d_in[2];
    const float* W1 = (const float*)d_in[3];
    const float* b1 = (const float*)d_in[4];
    const float* W2 = (const float*)d_in[5];
    const float* b2 = (const float*)d_in[6];
    const float* Wo = (const float*)d_in[7];
    const float* bo = (const float*)d_in[8];
    float* out = (float*)d_out;

    __bf16* A   = (__bf16*)d_ws;                       // [M_PAD][128]
    __bf16* H1  = A   + (size_t)M_PAD * IN_DIM;        // [M_PAD][256]
    __bf16* H2  = H1  + (size_t)M_PAD * HID_DIM;       // [M_PAD][256]
    __bf16* xb  = H2  + (size_t)M_PAD * HID_DIM;       // [N_NODES][128]
    __bf16* W1t = xb  + (size_t)N_NODES * IN_DIM;
    __bf16* W2t = W1t + IN_DIM * HID_DIM;
    __bf16* Wot = W2t + HID_DIM * HID_DIM;
    unsigned* pairBuf = (unsigned*)(Wot + HID_DIM * OUT_DIM);  // [NB*BCAP]
    int* nbr      = (int*)(pairBuf + (size_t)NB * BCAP);       // [NB*BCAP] strided CSR
    int* offsets  = nbr + (size_t)NB * BCAP;
    int* deg      = offsets + N_NODES;
    int* gcursor  = deg + N_NODES;

    // ---- fused init (replaces 2 memsets + 4 converts) ----
    init_kernel<<<(R_TOTAL + 255) / 256, 256, 0, stream>>>(x, W1, W2, Wo, xb, W1t, W2t, Wot,
                                                           out, gcursor);

    // ---- CSR build (bucket-strided; no global scan) ----
    bucket_v2_kernel<<<BKB, 256, 0, stream>>>(ei, gcursor, pairBuf);
    passB_kernel<<<NB, 256, 0, stream>>>(pairBuf, gcursor, nbr, offsets, deg);

    // ---- aggregate ----
    aggregate_kernel<<<(N_NODES + 3) / 4, 256, 0, stream>>>(xb, offsets, deg, nbr, A);

    // ---- MLP (weight-stationary bf16 MFMA, prefetched slab loop) ----
    const int NSTRIP_BLK = M_PAD / 32 / 4;  // 782
    gemm_ws<IN_DIM, HID_DIM, true, false><<<NSTRIP_BLK, 256, 0, stream>>>(A, W1t, b1, H1, nullptr);
    gemm_ws<HID_DIM, HID_DIM, true, false><<<NSTRIP_BLK, 256, 0, stream>>>(H1, W2t, b2, H2, nullptr);
    gemm_ws<HID_DIM, OUT_DIM, false, true><<<NSTRIP_BLK, 256, 0, stream>>>(H2, Wot, bo, out, bi);
}

// Round 10
// 337.084 us; speedup vs baseline: 5.8979x; 1.0817x over previous
//
#include <hip/hip_runtime.h>

#define N_NODES  100000
#define M_PAD    100096   // 782 * 128
#define N_EDGES  1600000
#define N_GRAPHS 512
#define IN_DIM   128
#define HID_DIM  256
#define OUT_DIM  128

#define NB       782      // buckets of 128 nodes
#define BCAP     3072     // mean 2048, +22 sigma headroom
#define CHUNK    2048     // edges per bucket_v2 block
#define BKB      ((N_EDGES + CHUNK - 1) / CHUNK)   // 782

typedef __bf16 bf16x8 __attribute__((ext_vector_type(8)));
typedef __bf16 bf16x4 __attribute__((ext_vector_type(4)));
typedef __bf16 bf16x2 __attribute__((ext_vector_type(2)));
typedef float  f32x4  __attribute__((ext_vector_type(4)));

// ---- packed weight buffer layout (frag-ordered; see init decode) ----
// L1: 32768 elems (8 slabs x 32cols x K=128), L2: 65536, L3: 32768
#define WP_L2_BASE 32768
#define WP_L3_BASE 98304
#define WP_TOTAL   131072

// ---------------- fused init ----------------
#define R_X    (N_NODES * IN_DIM / 4)           // x -> bf16, float4 granules
#define R_APAD ((M_PAD - N_NODES) * IN_DIM / 4) // zero A pad rows (bf16x4 granules)
#define R_WP   WP_TOTAL                         // weight pack
#define R_OUT  (N_GRAPHS * OUT_DIM / 4)
#define R_CUR  NB
#define R_TOTAL (R_X + R_APAD + R_WP + R_OUT + R_CUR)

__global__ __launch_bounds__(256) void init_kernel(const float* __restrict__ x,
                                                   const float* __restrict__ W1,
                                                   const float* __restrict__ W2,
                                                   const float* __restrict__ Wo,
                                                   __bf16* __restrict__ xb,
                                                   __bf16* __restrict__ Apad,  // A + N_NODES*IN_DIM
                                                   __bf16* __restrict__ Wp,
                                                   float* __restrict__ outbuf,
                                                   int* __restrict__ gcursor) {
    long long i = (long long)blockIdx.x * blockDim.x + threadIdx.x;
    if (i < R_X) {
        float4 v = ((const float4*)x)[i];
        bf16x4 h;
        h.x = (__bf16)v.x; h.y = (__bf16)v.y; h.z = (__bf16)v.z; h.w = (__bf16)v.w;
        ((bf16x4*)xb)[i] = h;
        return;
    }
    i -= R_X;
    if (i < R_APAD) {
        bf16x4 z; z.x = (__bf16)0.f; z.y = (__bf16)0.f; z.z = (__bf16)0.f; z.w = (__bf16)0.f;
        ((bf16x4*)Apad)[i] = z;
        return;
    }
    i -= R_APAD;
    if (i < R_WP) {
        // decode frag-ordered packed index -> (layer, k, n)
        int idx = (int)i;
        const float* src;
        int K, Nn, base;
        if (idx < WP_L2_BASE)      { src = W1; K = 128; Nn = 256; base = 0; }
        else if (idx < WP_L3_BASE) { src = W2; K = 256; Nn = 256; base = WP_L2_BASE; }
        else                       { src = Wo; K = 256; Nn = 128; base = WP_L3_BASE; }
        int r0 = idx - base;
        int slabElems = 32 * K;
        int j = r0 / slabElems;          // 32-col slab
        int r = r0 % slabElems;
        int KS = K / 32;
        int p = r >> 9;                  // frag index (512 elems each)
        int lane = (r >> 3) & 63;
        int e = r & 7;
        int s = p % KS, t = p / KS;
        int quad = lane >> 4, l16 = lane & 15;
        int n = j * 32 + t * 16 + l16;
        int k = s * 32 + quad * 8 + e;
        Wp[idx] = (__bf16)src[(size_t)k * Nn + n];
        return;
    }
    i -= R_WP;
    if (i < R_OUT) {
        ((float4*)outbuf)[i] = make_float4(0.f, 0.f, 0.f, 0.f);
        return;
    }
    i -= R_OUT;
    if (i < R_CUR) gcursor[i] = 0;
}

// ---------------- bucket_v2: LDS-staged edge binning ----------------
__global__ __launch_bounds__(256) void bucket_v2_kernel(const int* __restrict__ ei,
                                                        int* __restrict__ gcursor,
                                                        unsigned* __restrict__ pairBuf) {
    __shared__ int lcnt[NB];
    __shared__ int lbase[NB];
    const int tid = threadIdx.x;
    const int e0 = blockIdx.x * CHUNK;

    for (int b = tid; b < NB; b += 256) lcnt[b] = 0;
    __syncthreads();

    for (int i = tid; i < CHUNK; i += 256) {
        int e = e0 + i;
        if (e < N_EDGES) atomicAdd(&lcnt[ei[N_EDGES + e] >> 7], 1);
    }
    __syncthreads();

    for (int b = tid; b < NB; b += 256) {
        int c = lcnt[b];
        lbase[b] = c ? atomicAdd(&gcursor[b], c) : 0;
        lcnt[b] = 0;
    }
    __syncthreads();

    for (int i = tid; i < CHUNK; i += 256) {
        int e = e0 + i;
        if (e < N_EDGES) {
            int s = ei[e];
            int d = ei[N_EDGES + e];
            int b = d >> 7;
            int pos = lbase[b] + atomicAdd(&lcnt[b], 1);
            if (pos < BCAP)
                pairBuf[(size_t)b * BCAP + pos] = (unsigned)s | ((unsigned)(d & 127) << 17);
        }
    }
}

// ---------------- passB: per-bucket CSR build (bucket-strided) ----------------
__global__ __launch_bounds__(256) void passB_kernel(const unsigned* __restrict__ pairBuf,
                                                    const int* __restrict__ gcursor,
                                                    int* __restrict__ nbr,
                                                    int* __restrict__ offsets,
                                                    int* __restrict__ deg) {
    __shared__ int lcnt[128];
    __shared__ int loffs[128];
    __shared__ int lcur[128];
    const int b = blockIdx.x;
    const int tid = threadIdx.x;
    const int node0 = b << 7;
    const int cnt = min(gcursor[b], BCAP);
    const int base = b * BCAP;
    const unsigned* pb = pairBuf + (size_t)b * BCAP;

    if (tid < 128) { lcnt[tid] = 0; lcur[tid] = 0; }
    __syncthreads();

    for (int i = tid; i < cnt; i += 256)
        atomicAdd(&lcnt[pb[i] >> 17], 1);
    __syncthreads();

    if (tid < 128) loffs[tid] = lcnt[tid];
    __syncthreads();
    for (int st = 1; st < 128; st <<= 1) {
        int add = (tid < 128 && tid >= st) ? loffs[tid - st] : 0;
        __syncthreads();
        if (tid < 128) loffs[tid] += add;
        __syncthreads();
    }
    int excl = 0;
    if (tid < 128) {
        excl = loffs[tid] - lcnt[tid];
        int node = node0 + tid;
        if (node < N_NODES) {
            deg[node] = lcnt[tid];
            offsets[node] = base + excl;
        }
    }
    __syncthreads();
    if (tid < 128) loffs[tid] = excl;
    __syncthreads();

    for (int i = tid; i < cnt; i += 256) {
        unsigned u = pb[i];
        int dl = u >> 17;
        int slot = atomicAdd(&lcur[dl], 1);
        nbr[base + loffs[dl] + slot] = (int)(u & 0x1FFFF);
    }
}

// ---------------- gather aggregate (at memory floor) ----------------
__global__ __launch_bounds__(256) void aggregate_kernel(const __bf16* __restrict__ xb,
                                                        const int* __restrict__ offsets,
                                                        const int* __restrict__ deg,
                                                        const int* __restrict__ nbr,
                                                        __bf16* __restrict__ A) {
    int v = blockIdx.x * 4 + (threadIdx.x >> 6);
    v = __builtin_amdgcn_readfirstlane(v);
    int lane = threadIdx.x & 63;
    if (v >= N_NODES) return;
    int off = offsets[v];
    int len = deg[v];
    const int c0 = lane * 2;
    bf16x2 self = *(const bf16x2*)(xb + (size_t)v * IN_DIM + c0);
    float ax = (float)self.x, ay = (float)self.y;

    int addr = off + lane;
    if (addr > NB * BCAP - 1) addr = NB * BCAP - 1;
    int myidx = nbr[addr];

    int lim = len < 64 ? len : 64;
    int j = 0;
    for (; j + 8 <= lim; j += 8) {
        int s0 = __shfl(myidx, j + 0, 64);
        int s1 = __shfl(myidx, j + 1, 64);
        int s2 = __shfl(myidx, j + 2, 64);
        int s3 = __shfl(myidx, j + 3, 64);
        int s4 = __shfl(myidx, j + 4, 64);
        int s5 = __shfl(myidx, j + 5, 64);
        int s6 = __shfl(myidx, j + 6, 64);
        int s7 = __shfl(myidx, j + 7, 64);
        bf16x2 v0 = *(const bf16x2*)(xb + (size_t)s0 * IN_DIM + c0);
        bf16x2 v1 = *(const bf16x2*)(xb + (size_t)s1 * IN_DIM + c0);
        bf16x2 v2 = *(const bf16x2*)(xb + (size_t)s2 * IN_DIM + c0);
        bf16x2 v3 = *(const bf16x2*)(xb + (size_t)s3 * IN_DIM + c0);
        bf16x2 v4 = *(const bf16x2*)(xb + (size_t)s4 * IN_DIM + c0);
        bf16x2 v5 = *(const bf16x2*)(xb + (size_t)s5 * IN_DIM + c0);
        bf16x2 v6 = *(const bf16x2*)(xb + (size_t)s6 * IN_DIM + c0);
        bf16x2 v7 = *(const bf16x2*)(xb + (size_t)s7 * IN_DIM + c0);
        ax += (float)v0.x + (float)v1.x + (float)v2.x + (float)v3.x
            + (float)v4.x + (float)v5.x + (float)v6.x + (float)v7.x;
        ay += (float)v0.y + (float)v1.y + (float)v2.y + (float)v3.y
            + (float)v4.y + (float)v5.y + (float)v6.y + (float)v7.y;
    }
    for (; j < lim; ++j) {
        int s = __shfl(myidx, j, 64);
        bf16x2 vv = *(const bf16x2*)(xb + (size_t)s * IN_DIM + c0);
        ax += (float)vv.x;
        ay += (float)vv.y;
    }
    for (; j < len; ++j) {
        int s = nbr[off + j];
        bf16x2 vv = *(const bf16x2*)(xb + (size_t)s * IN_DIM + c0);
        ax += (float)vv.x;
        ay += (float)vv.y;
    }
    bf16x2 h;
    h.x = (__bf16)ax;
    h.y = (__bf16)ay;
    *(bf16x2*)(A + (size_t)v * IN_DIM + c0) = h;
}

// ---------------- fused 3-layer MLP + pool ----------------
// Block = 256 thr (4 waves), owns 128 rows; H tile lives in LDS across layers.
// H layout: row-major 128x256 bf16 with XOR chunk swizzle:
//   elem(row,col) -> H[row*256 + (((col>>3)+row)&31)*8 + (col&7)]
// A-frag read (16B chunk c=k/8): H + row*256 + (((c)+row)&31)*8  (conflict-free)
// Ws: per-slab weights, frag-ordered (p*64+lane)*8, straight copy from packed Wp.
__global__ __launch_bounds__(256) void mlp_fused(const __bf16* __restrict__ A,
                                                 const __bf16* __restrict__ Wp,
                                                 const float* __restrict__ b1,
                                                 const float* __restrict__ b2,
                                                 const float* __restrict__ bo,
                                                 float* __restrict__ out,
                                                 const int* __restrict__ batch) {
    __shared__ __bf16 H[128 * 256];   // 64 KB
    __shared__ __bf16 Ws[8192];       // 16 KB (max slab: 32 cols x K=256)

    const int tid  = threadIdx.x;
    const int wave = tid >> 6;
    const int lane = tid & 63;
    const int quad = lane >> 4, l16 = lane & 15;
    const int wrow = wave * 32;                     // local row base of this wave
    const size_t mblk = (size_t)blockIdx.x * 128;   // global row base of block

    // pool bookkeeping (rows of this wave)
    const int r0g = (int)mblk + wrow;
    int gfirst = (r0g < N_NODES) ? batch[r0g] : -2;
    int glast  = (r0g + 31 < N_NODES) ? batch[r0g + 31] : -1;

    bf16x8 a[2][8];

    // ---- layer 1 A-frags from global (K=128) ----
    #pragma unroll
    for (int i = 0; i < 2; ++i)
        #pragma unroll
        for (int s = 0; s < 4; ++s)
            a[i][s] = *(const bf16x8*)(A + (mblk + wrow + i * 16 + l16) * IN_DIM + s * 32 + quad * 8);

    // ---- layer 1: K=128 (KS=4), 8 slabs of 32 cols ----
    for (int j = 0; j < 8; ++j) {
        const __bf16* src = Wp + j * (32 * 128);
        #pragma unroll
        for (int c = tid; c < 512; c += 256)
            *(bf16x8*)(Ws + c * 8) = *(const bf16x8*)(src + c * 8);
        __syncthreads();

        f32x4 acc[2][2] = {};
        #pragma unroll
        for (int s = 0; s < 4; ++s)
            #pragma unroll
            for (int t = 0; t < 2; ++t) {
                bf16x8 b = *(const bf16x8*)(Ws + ((t * 4 + s) * 64 + lane) * 8);
                acc[0][t] = __builtin_amdgcn_mfma_f32_16x16x32_bf16(a[0][s], b, acc[0][t], 0, 0, 0);
                acc[1][t] = __builtin_amdgcn_mfma_f32_16x16x32_bf16(a[1][s], b, acc[1][t], 0, 0, 0);
            }
        #pragma unroll
        for (int i = 0; i < 2; ++i)
            #pragma unroll
            for (int t = 0; t < 2; ++t)
                #pragma unroll
                for (int rr = 0; rr < 4; ++rr) {
                    int row = wrow + i * 16 + quad * 4 + rr;
                    int col = j * 32 + t * 16 + l16;
                    float v = fmaxf(acc[i][t][rr] + b1[col], 0.f);
                    H[row * 256 + (((col >> 3) + row) & 31) * 8 + (col & 7)] = (__bf16)v;
                }
        __syncthreads();   // Ws reads done before next stage
    }

    // ---- layer 2 A-frags from LDS (own rows only -> no barrier needed) ----
    #pragma unroll
    for (int i = 0; i < 2; ++i)
        #pragma unroll
        for (int s = 0; s < 8; ++s) {
            int row = wrow + i * 16 + l16;
            a[i][s] = *(const bf16x8*)(H + row * 256 + (((s * 4 + quad) + row) & 31) * 8);
        }

    // ---- layer 2: K=256 (KS=8), 8 slabs of 32 cols, output overwrites H ----
    for (int j = 0; j < 8; ++j) {
        const __bf16* src = Wp + WP_L2_BASE + j * (32 * 256);
        #pragma unroll
        for (int c = tid; c < 1024; c += 256)
            *(bf16x8*)(Ws + c * 8) = *(const bf16x8*)(src + c * 8);
        __syncthreads();

        f32x4 acc[2][2] = {};
        #pragma unroll
        for (int s = 0; s < 8; ++s)
            #pragma unroll
            for (int t = 0; t < 2; ++t) {
                bf16x8 b = *(const bf16x8*)(Ws + ((t * 8 + s) * 64 + lane) * 8);
                acc[0][t] = __builtin_amdgcn_mfma_f32_16x16x32_bf16(a[0][s], b, acc[0][t], 0, 0, 0);
                acc[1][t] = __builtin_amdgcn_mfma_f32_16x16x32_bf16(a[1][s], b, acc[1][t], 0, 0, 0);
            }
        #pragma unroll
        for (int i = 0; i < 2; ++i)
            #pragma unroll
            for (int t = 0; t < 2; ++t)
                #pragma unroll
                for (int rr = 0; rr < 4; ++rr) {
                    int row = wrow + i * 16 + quad * 4 + rr;
                    int col = j * 32 + t * 16 + l16;
                    float v = fmaxf(acc[i][t][rr] + b2[col], 0.f);
                    H[row * 256 + (((col >> 3) + row) & 31) * 8 + (col & 7)] = (__bf16)v;
                }
        __syncthreads();
    }

    // ---- layer 3 A-frags from LDS ----
    #pragma unroll
    for (int i = 0; i < 2; ++i)
        #pragma unroll
        for (int s = 0; s < 8; ++s) {
            int row = wrow + i * 16 + l16;
            a[i][s] = *(const bf16x8*)(H + row * 256 + (((s * 4 + quad) + row) & 31) * 8);
        }

    // ---- layer 3: K=256, 4 slabs of 32 cols, pooled atomic output ----
    for (int j = 0; j < 4; ++j) {
        const __bf16* src = Wp + WP_L3_BASE + j * (32 * 256);
        #pragma unroll
        for (int c = tid; c < 1024; c += 256)
            *(bf16x8*)(Ws + c * 8) = *(const bf16x8*)(src + c * 8);
        __syncthreads();

        f32x4 acc[2][2] = {};
        #pragma unroll
        for (int s = 0; s < 8; ++s)
            #pragma unroll
            for (int t = 0; t < 2; ++t) {
                bf16x8 b = *(const bf16x8*)(Ws + ((t * 8 + s) * 64 + lane) * 8);
                acc[0][t] = __builtin_amdgcn_mfma_f32_16x16x32_bf16(a[0][s], b, acc[0][t], 0, 0, 0);
                acc[1][t] = __builtin_amdgcn_mfma_f32_16x16x32_bf16(a[1][s], b, acc[1][t], 0, 0, 0);
            }

        if (gfirst == glast) {
            // whole 32-row strip in one graph: 1 atomic per column
            #pragma unroll
            for (int t = 0; t < 2; ++t) {
                float sum = 0.f;
                #pragma unroll
                for (int i = 0; i < 2; ++i)
                    #pragma unroll
                    for (int rr = 0; rr < 4; ++rr) sum += acc[i][t][rr];
                sum += __shfl_xor(sum, 16, 64);
                sum += __shfl_xor(sum, 32, 64);
                if (quad == 0) {
                    int c = j * 32 + t * 16 + l16;
                    atomicAdd(out + (size_t)gfirst * OUT_DIM + c, sum + 32.f * bo[c]);
                }
            }
        } else {
            #pragma unroll
            for (int i = 0; i < 2; ++i)
                #pragma unroll
                for (int rr = 0; rr < 4; ++rr) {
                    int m = r0g + i * 16 + quad * 4 + rr;
                    if (m < N_NODES) {
                        int g = batch[m];
                        #pragma unroll
                        for (int t = 0; t < 2; ++t) {
                            int c = j * 32 + t * 16 + l16;
                            atomicAdd(out + (size_t)g * OUT_DIM + c, acc[i][t][rr] + bo[c]);
                        }
                    }
                }
        }
        __syncthreads();
    }
}

extern "C" void kernel_launch(void* const* d_in, const int* in_sizes, int n_in,
                              void* d_out, int out_size, void* d_ws, size_t ws_size,
                              hipStream_t stream) {
    const float* x  = (const float*)d_in[0];
    const int*   ei = (const int*)d_in[1];
    const int*   bi = (const int*)d_in[2];
    const float* W1 = (const float*)d_in[3];
    const float* b1 = (const float*)d_in[4];
    const float* W2 = (const float*)d_in[5];
    const float* b2 = (const float*)d_in[6];
    const float* Wo = (const float*)d_in[7];
    const float* bo = (const float*)d_in[8];
    float* out = (float*)d_out;

    __bf16* A  = (__bf16*)d_ws;                        // [M_PAD][128]
    __bf16* xb = A + (size_t)M_PAD * IN_DIM;           // [N_NODES][128]
    __bf16* Wp = xb + (size_t)N_NODES * IN_DIM;        // [131072] packed frag-ordered
    unsigned* pairBuf = (unsigned*)(Wp + WP_TOTAL);    // [NB*BCAP]
    int* nbr      = (int*)(pairBuf + (size_t)NB * BCAP);  // [NB*BCAP] strided CSR
    int* offsets  = nbr + (size_t)NB * BCAP;
    int* deg      = offsets + N_NODES;
    int* gcursor  = deg + N_NODES;

    // ---- fused init: x->bf16, zero A-pad rows, pack weights, zero out & cursors ----
    init_kernel<<<(R_TOTAL + 255) / 256, 256, 0, stream>>>(
        x, W1, W2, Wo, xb, A + (size_t)N_NODES * IN_DIM, Wp, out, gcursor);

    // ---- CSR build ----
    bucket_v2_kernel<<<BKB, 256, 0, stream>>>(ei, gcursor, pairBuf);
    passB_kernel<<<NB, 256, 0, stream>>>(pairBuf, gcursor, nbr, offsets, deg);

    // ---- aggregate ----
    aggregate_kernel<<<(N_NODES + 3) / 4, 256, 0, stream>>>(xb, offsets, deg, nbr, A);

    // ---- fused MLP + pool ----
    mlp_fused<<<M_PAD / 128, 256, 0, stream>>>(A, Wp, b1, b2, bo, out, bi);
}